// Round 8
// baseline (636.331 us; speedup 1.0000x reference)
//
#include <hip/hip_runtime.h>
#include <hip/hip_bf16.h>
#include <cstdint>
#include <type_traits>

typedef unsigned short u16;
typedef __bf16 bf16x8 __attribute__((ext_vector_type(8)));
typedef float f32x4 __attribute__((ext_vector_type(4)));

#define LN_EPS 1e-6f

enum { BIAS_NONE = 0, BIAS_COL = 1, BIAS_ROW = 2, BIAS_COL2 = 3 };

__device__ __forceinline__ float b2f(u16 h) {
  union { unsigned u; float f; } v;
  v.u = ((unsigned)h) << 16;
  return v.f;
}
__device__ __forceinline__ u16 f2b(float x) {
  return __bfloat16_as_ushort(__float2bfloat16(x));
}

__device__ __forceinline__ void gld_lds16(const void* g, void* l) {
  __builtin_amdgcn_global_load_lds(
      (const __attribute__((address_space(1))) void*)g,
      (__attribute__((address_space(3))) void*)l, 16, 0, 0);
}

// 8x f32 -> 8x bf16, one 16B store.
__device__ __forceinline__ void st8(float4 a, float4 b, u16* dst) {
  u16 t[8] = {f2b(a.x), f2b(a.y), f2b(a.z), f2b(a.w),
              f2b(b.x), f2b(b.y), f2b(b.z), f2b(b.w)};
  *reinterpret_cast<uint4*>(dst) = *reinterpret_cast<const uint4*>(t);
}

__device__ __forceinline__ void stage8_cvt(const float* src, size_t off,
                                           u16* dst) {
  const float* p = src + off;
  st8(*reinterpret_cast<const float4*>(p),
      *reinterpret_cast<const float4*>(p + 4), dst);
}

// C[M,N](ldc) = A[M,K](lda) * B[N,K](ldb)^T (+bias)(+relu)(+C if CACC).
// K mult of BK. Dual-operand batching: staged A row r uses (r < Msplit ?
// A : A2) at local row (r - Msplit); B and row-selected bias per block
// row: bm<Msplit?B:B2. BIAS_COL: bp[gc]. BIAS_COL2: gc<colsplit ?
// bias[gc] : bias2[gc-colsplit]. BIAS_ROW: bp[gr & rowmask].
// CACC: epilogue v += C[gr*ldc+gc] (f32 split-K accumulation; producer
// pass must be a prior dispatch).
// A_RAW/B_RAW: f32 source, global->reg prefetch at loop top, cvt+ds_write
// after MFMA; bf16 source staged via global_load_lds (issued at loop top).
// Double-buffered LDS, one barrier per BK-step. BK=64 = two 32-wide
// subtiles, half-major LDS layout (all swizzle math per 32-subtile).
// LDS 16B-chunk XOR-swizzled with (row>>1)&3 (linear dest + pre-swizzled
// source column + swizzled read) -> 0 bank conflicts (verified r1).
// Wave maps: NT=512: 8 waves 4x2 of 32x64 (TM=TN=128, 32KB LDS). NT=256:
// 128x128 -> 2x2 waves of 64x64 (m97 shape, 16 MFMA : 8 ds_read per
// wave-step -- best ratio); 128x64 -> 4x1 of 32x64; 64x64 -> 2x2 of 32x32.
// LB = launch-bounds min-waves/EU (r5 lesson: this is the occupancy cap;
// raise to the LDS/VGPR limit). Latency regime: waves-in-flight dominate.
template <typename OutT, int BIAS, bool RELU, bool A_RAW, bool B_RAW, int TM,
          int TN, int BK, int NT, int LB, bool CACC>
__global__ __launch_bounds__(NT, LB) void gemm_db(
    const void* __restrict__ A, const void* __restrict__ A2,
    const void* __restrict__ B, const void* __restrict__ B2,
    const float* __restrict__ bias, const float* __restrict__ bias2,
    OutT* __restrict__ C, int M, int N, int K, int lda, int ldb, int MA,
    int NB, int ldc, int Msplit, int rowmask, int colsplit) {
  constexpr int SA = (TM * BK) / (NT * 8);  // A staging slots
  constexpr int SB = (TN * BK) / (NT * 8);
  constexpr int AI = (NT == 512) ? 2 : ((TM == 128 && TN == 128) ? 4 : 2);
  constexpr int BJ = (TM == 64 && TN == 64) ? 2 : 4;
  __shared__ __align__(16) u16 As[2][TM * BK];
  __shared__ __align__(16) u16 Bs[2][TN * BK];
  const int tid = threadIdx.x;
  const int lane = tid & 63;
  const int wv = tid >> 6;
  int wr, wc;
  if constexpr (NT == 512) {
    wr = (wv & 3) * 32; wc = (wv >> 2) * 64;
  } else if constexpr (TM == 128 && TN == 128) {
    wr = (wv >> 1) * 64; wc = (wv & 1) * 64;
  } else if constexpr (TM == 128 && TN == 64) {
    wr = wv * 32; wc = 0;
  } else {
    wr = (wv >> 1) * 32; wc = (wv & 1) * 32;
  }
  const int mrow = lane & 15;
  const int quad = lane >> 4;

  // Bijective XCD swizzle (all grids here are %8==0; identity otherwise).
  int bxi = blockIdx.x, byi = blockIdx.y;
  {
    const int gx = (int)gridDim.x;
    const int nwg = gx * (int)gridDim.y;
    if ((nwg & 7) == 0) {
      int wg = byi * gx + bxi;
      wg = (wg & 7) * (nwg >> 3) + (wg >> 3);
      bxi = wg % gx;
      byi = wg / gx;
    }
  }
  const int bm = byi * TM;
  const int bn = bxi * TN;

  f32x4 acc[AI][BJ];
#pragma unroll
  for (int i = 0; i < AI; i++)
#pragma unroll
    for (int j = 0; j < BJ; j++) acc[i][j] = f32x4{0.f, 0.f, 0.f, 0.f};

  // Staging: NT threads x 8 elems (16B) per slot; half-major linear LDS.
  // Slot s covers elems [s*NT*8, (s+1)*NT*8) of (half, row, col32) order.
  const int e0 = tid * 8;
  const int r0t = e0 >> 5;  // row within slot row-span
  const int swc8 = ((((e0 >> 3) & 3) ^ ((r0t >> 1) & 3)) << 3);

  const void* Asrc[SA];
  size_t aoff[SA];
#pragma unroll
  for (int s = 0; s < SA; s++) {
    const int h = (s * NT * 8) / (TM * 32);
    const int rb = ((s * NT * 8) % (TM * 32)) >> 5;
    int ra = bm + rb + r0t;
    if (ra >= MA) ra = MA - 1;
    Asrc[s] = (ra < Msplit) ? A : A2;
    const int rr = (ra < Msplit) ? ra : ra - Msplit;
    aoff[s] = (size_t)rr * lda + h * 32 + swc8;
  }
  const void* Bb = (bm < Msplit) ? B : B2;
  size_t boff[SB];
#pragma unroll
  for (int s = 0; s < SB; s++) {
    const int h = (s * NT * 8) / (TN * 32);
    const int rb = ((s * NT * 8) % (TN * 32)) >> 5;
    int rbn = bn + rb + r0t;
    if (rbn >= NB) rbn = NB - 1;
    boff[s] = (size_t)rbn * ldb + h * 32 + swc8;
  }

  // ---- prologue: stage k=0 into buffer 0
#pragma unroll
  for (int s = 0; s < SA; s++) {
    if constexpr (A_RAW) {
      const float* p = (const float*)Asrc[s] + aoff[s];
      st8(*reinterpret_cast<const float4*>(p),
          *reinterpret_cast<const float4*>(p + 4), &As[0][s * NT * 8 + e0]);
    } else {
      gld_lds16((const u16*)Asrc[s] + aoff[s], &As[0][s * NT * 8 + e0]);
    }
  }
#pragma unroll
  for (int s = 0; s < SB; s++) {
    if constexpr (B_RAW) {
      const float* p = (const float*)Bb + boff[s];
      st8(*reinterpret_cast<const float4*>(p),
          *reinterpret_cast<const float4*>(p + 4), &Bs[0][s * NT * 8 + e0]);
    } else {
      gld_lds16((const u16*)Bb + boff[s], &Bs[0][s * NT * 8 + e0]);
    }
  }
  __syncthreads();

  // Read-side swizzle: chunk quad of row (16a+mrow) is at quad^((mrow>>1)&3).
  const int so = ((quad ^ ((mrow >> 1) & 3)) << 3);

  int cur = 0;
  for (int k0 = 0; k0 < K; k0 += BK) {
    const int nk = k0 + BK;
    const bool pf = nk < K;
    float4 fA[SA][2], fB[SB][2];
    if (pf) {
#pragma unroll
      for (int s = 0; s < SA; s++) {
        if constexpr (A_RAW) {
          const float* p = (const float*)Asrc[s] + aoff[s] + nk;
          fA[s][0] = *reinterpret_cast<const float4*>(p);
          fA[s][1] = *reinterpret_cast<const float4*>(p + 4);
        } else {
          gld_lds16((const u16*)Asrc[s] + aoff[s] + nk,
                    &As[cur ^ 1][s * NT * 8 + e0]);
        }
      }
#pragma unroll
      for (int s = 0; s < SB; s++) {
        if constexpr (B_RAW) {
          const float* p = (const float*)Bb + boff[s] + nk;
          fB[s][0] = *reinterpret_cast<const float4*>(p);
          fB[s][1] = *reinterpret_cast<const float4*>(p + 4);
        } else {
          gld_lds16((const u16*)Bb + boff[s] + nk,
                    &Bs[cur ^ 1][s * NT * 8 + e0]);
        }
      }
    }
    // compute on buffer `cur` (BK/32 halves)
#pragma unroll
    for (int h = 0; h < BK / 32; h++) {
      bf16x8 af[AI], bfm[BJ];
#pragma unroll
      for (int i = 0; i < AI; i++)
        af[i] = *reinterpret_cast<const bf16x8*>(
            &As[cur][h * TM * 32 + (wr + i * 16 + mrow) * 32 + so]);
#pragma unroll
      for (int j = 0; j < BJ; j++)
        bfm[j] = *reinterpret_cast<const bf16x8*>(
            &Bs[cur][h * TN * 32 + (wc + j * 16 + mrow) * 32 + so]);
#pragma unroll
      for (int i = 0; i < AI; i++)
#pragma unroll
        for (int j = 0; j < BJ; j++)
          acc[i][j] = __builtin_amdgcn_mfma_f32_16x16x32_bf16(
              af[i], bfm[j], acc[i][j], 0, 0, 0);
    }
    // late half of RAW staging: cvt + ds_write into next buffer
    if (pf) {
      if constexpr (A_RAW) {
#pragma unroll
        for (int s = 0; s < SA; s++)
          st8(fA[s][0], fA[s][1], &As[cur ^ 1][s * NT * 8 + e0]);
      }
      if constexpr (B_RAW) {
#pragma unroll
        for (int s = 0; s < SB; s++)
          st8(fB[s][0], fB[s][1], &Bs[cur ^ 1][s * NT * 8 + e0]);
      }
    }
    __syncthreads();
    cur ^= 1;
  }

  const float* bp = (bm < Msplit) ? bias : bias2;
#pragma unroll
  for (int i = 0; i < AI; i++) {
#pragma unroll
    for (int j = 0; j < BJ; j++) {
#pragma unroll
      for (int r = 0; r < 4; r++) {
        const int gr = bm + wr + i * 16 + quad * 4 + r;
        const int gc = bn + wc + j * 16 + mrow;
        if (gr < M && gc < N) {
          float v = acc[i][j][r];
          if (BIAS == BIAS_COL) v += bp[gc];
          if (BIAS == BIAS_COL2)
            v += (gc < colsplit) ? bias[gc] : bias2[gc - colsplit];
          if (BIAS == BIAS_ROW) v += bp[gr & rowmask];
          if (CACC) v += (float)C[(size_t)gr * ldc + gc];
          if (RELU) v = fmaxf(v, 0.f);
          if constexpr (std::is_same<OutT, float>::value)
            C[(size_t)gr * ldc + gc] = v;
          else
            C[(size_t)gr * ldc + gc] = f2b(v);
        }
      }
    }
  }
}

// Up-to-3-segment f32 -> bf16 bulk conversion; blocksPer blocks/segment,
// each segment exactly blocksPer*256*8 elems.
__global__ __launch_bounds__(256) void cvt3_k(
    const float* __restrict__ s0, u16* __restrict__ d0,
    const float* __restrict__ s1, u16* __restrict__ d1,
    const float* __restrict__ s2, u16* __restrict__ d2, int blocksPer) {
  const int seg = blockIdx.x / blocksPer;
  const int b = blockIdx.x % blocksPer;
  const float* s = (seg == 0) ? s0 : ((seg == 1) ? s1 : s2);
  u16* d = (seg == 0) ? d0 : ((seg == 1) ? d1 : d2);
  const size_t i = ((size_t)b * 256 + threadIdx.x) * 8;
  stage8_cvt(s, i, d + i);
}

// Transposed bf16 conversion: dst[d][j] = bf16(src[j][d]), 1024x1024.
__global__ __launch_bounds__(256) void wqt_k(const float* __restrict__ src,
                                             u16* __restrict__ dst) {
  __shared__ float t[64][65];
  const int bx = blockIdx.x;  // d-tile
  const int by = blockIdx.y;  // j-tile
  const int tx = threadIdx.x & 63;
  const int ty = threadIdx.x >> 6;
#pragma unroll
  for (int i = 0; i < 16; i++)
    t[ty * 16 + i][tx] =
        src[(size_t)(by * 64 + ty * 16 + i) * 1024 + bx * 64 + tx];
  __syncthreads();
#pragma unroll
  for (int i = 0; i < 16; i++)
    dst[(size_t)(bx * 64 + ty * 16 + i) * 1024 + by * 64 + tx] =
        f2b(t[tx][ty * 16 + i]);
}

// kb[b*224+s] = sum_j bf16(Kc[(b*196+s)*ld + j]) * bq[j] (s<196; else 0).
__global__ __launch_bounds__(256) void kb_k(const u16* __restrict__ Kc,
                                            const float* __restrict__ bq,
                                            float* __restrict__ kb, int ld) {
  const int wvi = blockIdx.x * 4 + (threadIdx.x >> 6);  // 0..447
  const int lane = threadIdx.x & 63;
  const int b = wvi / 224, s = wvi % 224;
  float sum = 0.f;
  if (s < 196) {
    const u16* row = Kc + (size_t)(b * 196 + s) * ld;
    for (int j = lane; j < 1024; j += 64) sum += b2f(row[j]) * bq[j];
  }
#pragma unroll
  for (int off = 32; off > 0; off >>= 1) sum += __shfl_xor(sum, off);
  if (lane == 0) kb[wvi] = sum;
}

// In-place softmax over Sp[row, 0..224) bf16 (16384 batched rows):
// p = softmax((s + score)/8) over cols < 196; cols 196..223 zeroed.
__global__ __launch_bounds__(256) void softmax_k(
    u16* __restrict__ Sp, const float* __restrict__ sc1,
    const float* __restrict__ sc2) {
  const int row = blockIdx.x * 4 + (threadIdx.x >> 6);
  const int lane = threadIdx.x & 63;
  const float* score = (row < 8192) ? sc1 + (size_t)row * 196
                                    : sc2 + (size_t)(row - 8192) * 196;
  float x[4];
  float mx = -1e30f;
#pragma unroll
  for (int t = 0; t < 4; t++) {
    const int s = lane + 64 * t;
    float v = -1e30f;
    if (s < 196) v = (b2f(Sp[(size_t)row * 224 + s]) + score[s]) * 0.125f;
    x[t] = v;
    mx = fmaxf(mx, v);
  }
#pragma unroll
  for (int off = 32; off > 0; off >>= 1) mx = fmaxf(mx, __shfl_xor(mx, off));
  float sum = 0.f;
#pragma unroll
  for (int t = 0; t < 4; t++) {
    const int s = lane + 64 * t;
    const float e = (s < 196) ? expf(x[t] - mx) : 0.f;
    x[t] = e;
    sum += e;
  }
#pragma unroll
  for (int off = 32; off > 0; off >>= 1) sum += __shfl_xor(sum, off);
  const float inv = 1.f / sum;
#pragma unroll
  for (int t = 0; t < 4; t++) {
    const int s = lane + 64 * t;
    if (s < 224) Sp[(size_t)row * 224 + s] = f2b((s < 196) ? x[t] * inv : 0.f);
  }
}

// Fused both-branch residual-LN-pool: block row16 in [0,16384);
// branch = row16>>13 selects text/colbase. t = LN(X + Y)*g + be (D=1024);
// pooled[row, colbase+i] = max(t[2i], t[2i+1]).
__global__ __launch_bounds__(256) void ln_pool_k(
    const float* __restrict__ X1, const float* __restrict__ X2,
    const u16* __restrict__ Y, const float* __restrict__ g,
    const float* __restrict__ be, u16* __restrict__ pooled) {
  const int row16 = blockIdx.x;
  const int br = row16 >> 13;
  const int row = row16 & 8191;
  const int tid = threadIdx.x;
  const int lane = tid & 63;
  const int wv = tid >> 6;
  const float* X = (br ? X2 : X1) + (size_t)row * 1024;
  const u16* Yp = Y + (size_t)row16 * 1024;
  __shared__ float red[4];
  float v[4];
  float s = 0.f;
#pragma unroll
  for (int j = 0; j < 4; j++) {
    const float a = X[tid * 4 + j] + b2f(Yp[tid * 4 + j]);
    v[j] = a;
    s += a;
  }
#pragma unroll
  for (int off = 32; off > 0; off >>= 1) s += __shfl_xor(s, off);
  if (lane == 0) red[wv] = s;
  __syncthreads();
  const float mu = (red[0] + red[1] + red[2] + red[3]) * (1.f / 1024.f);
  __syncthreads();
  float var = 0.f;
#pragma unroll
  for (int j = 0; j < 4; j++) {
    const float d = v[j] - mu;
    var += d * d;
  }
#pragma unroll
  for (int off = 32; off > 0; off >>= 1) var += __shfl_xor(var, off);
  if (lane == 0) red[wv] = var;
  __syncthreads();
  var = (red[0] + red[1] + red[2] + red[3]) * (1.f / 1024.f);
  const float rs = rsqrtf(var + LN_EPS);
  float n[4];
#pragma unroll
  for (int j = 0; j < 4; j++)
    n[j] = (v[j] - mu) * rs * g[tid * 4 + j] + be[tid * 4 + j];
  const size_t pb = (size_t)row * 1024 + br * 512 + tid * 2;
  pooled[pb] = f2b(fmaxf(n[0], n[1]));
  pooled[pb + 1] = f2b(fmaxf(n[2], n[3]));
}

// out(f32) = LN(X(bf16) + Y(f32))*g + be over D=1024. In-place safe when
// out == Y: each block owns one row; every thread reads its own elements
// before any thread of the block writes them; rows are block-disjoint.
__global__ __launch_bounds__(256) void ln_out_f_k(
    const u16* __restrict__ X, const float* __restrict__ Y,
    const float* __restrict__ g, const float* __restrict__ be,
    float* __restrict__ out) {
  const int row = blockIdx.x;
  const int tid = threadIdx.x;
  const int lane = tid & 63;
  const int wv = tid >> 6;
  __shared__ float red[4];
  float v[4];
  float s = 0.f;
  const size_t base = (size_t)row * 1024 + tid * 4;
#pragma unroll
  for (int j = 0; j < 4; j++) {
    const float a = b2f(X[base + j]) + Y[base + j];
    v[j] = a;
    s += a;
  }
#pragma unroll
  for (int off = 32; off > 0; off >>= 1) s += __shfl_xor(s, off);
  if (lane == 0) red[wv] = s;
  __syncthreads();
  const float mu = (red[0] + red[1] + red[2] + red[3]) * (1.f / 1024.f);
  __syncthreads();
  float var = 0.f;
#pragma unroll
  for (int j = 0; j < 4; j++) {
    const float d = v[j] - mu;
    var += d * d;
  }
#pragma unroll
  for (int off = 32; off > 0; off >>= 1) var += __shfl_xor(var, off);
  if (lane == 0) red[wv] = var;
  __syncthreads();
  var = (red[0] + red[1] + red[2] + red[3]) * (1.f / 1024.f);
  const float rs = rsqrtf(var + LN_EPS);
#pragma unroll
  for (int j = 0; j < 4; j++)
    out[base + j] = (v[j] - mu) * rs * g[tid * 4 + j] + be[tid * 4 + j];
}

extern "C" void kernel_launch(void* const* d_in, const int* in_sizes, int n_in,
                              void* d_out, int out_size, void* d_ws,
                              size_t ws_size, hipStream_t stream) {
  const size_t MB = 1ull << 20;
  if (ws_size < 61 * MB) return;  // proven >= 61 MiB

  const float* text1 = (const float*)d_in[0];
  const float* vis1 = (const float*)d_in[1];
  const float* sc1 = (const float*)d_in[2];
  const float* text2 = (const float*)d_in[3];
  const float* vis2 = (const float*)d_in[4];
  const float* sc2 = (const float*)d_in[5];
  const float* Wq = (const float*)d_in[6];
  const float* bq = (const float*)d_in[7];
  const float* Wk = (const float*)d_in[8];
  const float* bk = (const float*)d_in[9];
  const float* Wv = (const float*)d_in[10];
  const float* bv = (const float*)d_in[11];
  const float* Wo = (const float*)d_in[12];
  const float* bo = (const float*)d_in[13];
  const float* W1 = (const float*)d_in[14];
  const float* b1 = (const float*)d_in[15];
  const float* W2 = (const float*)d_in[16];
  const float* b2 = (const float*)d_in[17];
  const float* g1 = (const float*)d_in[18];
  const float* be1 = (const float*)d_in[19];
  const float* g2 = (const float*)d_in[20];
  const float* be2 = (const float*)d_in[21];

  const int D = 1024, Sv = 196, SvP = 224, DFF = 4096;
  const int M2 = 16384;
  char* w = (char*)d_ws;
  // Algebra (r4): S = text·(K·Wq)^T + (K·bq)^T ; O = P·(V·Wo^T+1·bo^T)^T.
  // FFN (r8): chunk along DFF columns; F accumulates f32 directly in
  // d_out (exact [8192,1024] f32 shape, dead until ln_out); W1/W2 read
  // RAW f32 (no FFN weight cvt); ln_out one launch, in-place on d_out.
  // ws layout (peak 48 MiB <= proven 61):
  //  [0,16)  pooled bf16 [8192,1024] (persists)
  //  [16,18) Wkb [18,20) Wvb (contiguous: stacked B for KVcat GEMM)
  //  [20,22) Wob [22,24) WqT
  //  [24,..) KVcat [392,2048] 1.53M  [26,..) K2cat [392,1024] 784K
  //  [27,..) VWoT [2048,224] 896K    [28,..) kb f32[448]
  //  [29,36) Spcat bf16 [16384,224] 7 MB
  //  Ocat: d_out (32 MB bf16 scratch; dead until FFN)
  //  Phase B: [16,48) H bf16 [8192,2048]; Fp f32 = d_out.
  u16* pooled = (u16*)(w + 0 * MB);
  u16* Wkb = (u16*)(w + 16 * MB);  // KVcat B-panel = Wkb..Wvb stacked
  u16* Wvb = (u16*)(w + 18 * MB);
  u16* Wob = (u16*)(w + 20 * MB);
  u16* WqT = (u16*)(w + 22 * MB);
  u16* KVcat = (u16*)(w + 24 * MB);
  u16* K2cat = (u16*)(w + 26 * MB);
  u16* VWoT = (u16*)(w + 27 * MB);
  float* kb = (float*)(w + 28 * MB);
  u16* Spcat = (u16*)(w + 29 * MB);
  u16* Ocat = (u16*)d_out;
  u16* H = (u16*)(w + 16 * MB);
  float* Fp = (float*)d_out;

  auto grid = [](int m, int n, int tm, int tn) {
    return dim3((unsigned)((n + tn - 1) / tn), (unsigned)((m + tm - 1) / tm));
  };

  // Attention weights to bf16: Wk/Wv/Wo fused (512 blocks each); Wq
  // transposed (needed as K·Wq).
  cvt3_k<<<dim3(3 * 512), 256, 0, stream>>>(Wk, Wkb, Wv, Wvb, Wo, Wob, 512);
  wqt_k<<<dim3(16, 16), 256, 0, stream>>>(Wq, WqT);

  // KVcat[392,2048] = [vis1;vis2](raw f32) @ [Wk;Wv]^T + [bk|bv]
  gemm_db<u16, BIAS_COL2, false, true, false, 64, 64, 32, 256, 8, false>
      <<<grid(2 * Sv, 2 * D, 64, 64), 256, 0, stream>>>(
          vis1, vis2, Wkb, Wkb, bk, bv, KVcat, 2 * Sv, 2 * D, D, D, D, 2 * Sv,
          2 * D, 2 * D, Sv, 0, D);
  // K2cat[392,1024] = Kcat(lda=2048) @ Wq
  gemm_db<u16, BIAS_NONE, false, false, false, 64, 64, 32, 256, 8, false>
      <<<grid(2 * Sv, D, 64, 64), 256, 0, stream>>>(
          KVcat, KVcat, WqT, WqT, nullptr, nullptr, K2cat, 2 * Sv, D, D, 2 * D,
          D, 2 * Sv, D, D, 2 * Sv, 0, 0);
  // kb[2][224] = Kcat · bq
  kb_k<<<dim3(112), 256, 0, stream>>>(KVcat, bq, kb, 2 * D);
  // Spcat[16384,ldc=224] = textcat(raw f32) @ K2_br^T + kb_br (row-half)
  gemm_db<u16, BIAS_COL, false, true, false, 64, 64, 32, 256, 8, false>
      <<<grid(M2, Sv, 64, 64), 256, 0, stream>>>(
          text1, text2, K2cat, K2cat + (size_t)Sv * D, kb, kb + SvP, Spcat, M2,
          Sv, D, D, D, M2, Sv, SvP, 8192, 0, 0);
  // softmax((Sp + score)/8), pad zeros
  softmax_k<<<dim3(M2 / 4), 256, 0, stream>>>(Spcat, sc1, sc2);
  // VWoT[2048,224]: row b*1024+n = Wo[n]·V_br[s] + bo[n]
  gemm_db<u16, BIAS_ROW, false, false, false, 64, 64, 32, 256, 8, false>
      <<<grid(2 * D, SvP, 64, 64), 256, 0, stream>>>(
          Wob, Wob, KVcat + D, KVcat + (size_t)Sv * 2 * D + D, bo, bo, VWoT,
          2 * D, SvP, D, D, 2 * D, 2 * D, Sv, SvP, D, D - 1, 0);
  // Ocat[16384,1024] = Spcat @ VWoT_br^T, K=224 (d_out scratch) -- 4096 blk
  gemm_db<u16, BIAS_NONE, false, false, false, 64, 64, 32, 256, 8, false>
      <<<grid(M2, D, 64, 64), 256, 0, stream>>>(
          Spcat, Spcat + (size_t)8192 * SvP, VWoT, VWoT + (size_t)D * SvP,
          nullptr, nullptr, Ocat, M2, D, SvP, SvP, SvP, M2, D, D, 8192, 0, 0);
  // fused both-branch residual + LN + maxpool -> pooled
  ln_pool_k<<<dim3(M2), 256, 0, stream>>>(text1, text2, Ocat, g1, be1, pooled);

  // FFN: for each DFF-column half c:
  //   H[8192,2048] = relu(pooled @ W1[c-half]^T + b1[c-half])  (B raw f32)
  //   Fp (+)= H @ W2[:,c-half]^T  (f32 accumulate in d_out; +b2 on c=0)
  for (int c = 0; c < 2; ++c) {
    const size_t wo1 = (size_t)c * 2048 * D;  // W1 row offset
    gemm_db<u16, BIAS_COL, true, false, true, 128, 128, 32, 256, 4, false>
        <<<grid(8192, 2048, 128, 128), 256, 0, stream>>>(
            pooled, pooled, W1 + wo1, W1 + wo1, b1 + c * 2048, b1 + c * 2048,
            H, 8192, 2048, D, D, D, 8192, 2048, 2048, 8192, 0, 0);
    if (c == 0) {
      gemm_db<float, BIAS_COL, false, false, true, 64, 64, 32, 256, 8, false>
          <<<grid(8192, D, 64, 64), 256, 0, stream>>>(
              H, H, W2, W2, b2, b2, Fp, 8192, D, 2048, 2048, DFF, 8192, D, D,
              8192, 0, 0);
    } else {
      gemm_db<float, BIAS_NONE, false, false, true, 64, 64, 32, 256, 8, true>
          <<<grid(8192, D, 64, 64), 256, 0, stream>>>(
              H, H, W2 + 2048, W2 + 2048, nullptr, nullptr, Fp, 8192, D, 2048,
              2048, DFF, 8192, D, D, 8192, 0, 0);
    }
  }
  // out = LN(pooled + Fp) in-place on d_out -- one 8192-block launch
  ln_out_f_k<<<dim3(8192), 256, 0, stream>>>(pooled, Fp, g2, be2,
                                             (float*)d_out);
}

// Round 9
// 556.589 us; speedup vs baseline: 1.1433x; 1.1433x over previous
//
#include <hip/hip_runtime.h>
#include <hip/hip_bf16.h>
#include <cstdint>
#include <type_traits>

typedef unsigned short u16;
typedef __bf16 bf16x8 __attribute__((ext_vector_type(8)));
typedef float f32x4 __attribute__((ext_vector_type(4)));

#define LN_EPS 1e-6f

enum { BIAS_NONE = 0, BIAS_COL = 1, BIAS_ROW = 2, BIAS_COL2 = 3 };

__device__ __forceinline__ float b2f(u16 h) {
  union { unsigned u; float f; } v;
  v.u = ((unsigned)h) << 16;
  return v.f;
}
__device__ __forceinline__ u16 f2b(float x) {
  return __bfloat16_as_ushort(__float2bfloat16(x));
}

__device__ __forceinline__ void gld_lds16(const void* g, void* l) {
  __builtin_amdgcn_global_load_lds(
      (const __attribute__((address_space(1))) void*)g,
      (__attribute__((address_space(3))) void*)l, 16, 0, 0);
}

// 8x f32 -> 8x bf16, one 16B store.
__device__ __forceinline__ void st8(float4 a, float4 b, u16* dst) {
  u16 t[8] = {f2b(a.x), f2b(a.y), f2b(a.z), f2b(a.w),
              f2b(b.x), f2b(b.y), f2b(b.z), f2b(b.w)};
  *reinterpret_cast<uint4*>(dst) = *reinterpret_cast<const uint4*>(t);
}

__device__ __forceinline__ void stage8_cvt(const float* src, size_t off,
                                           u16* dst) {
  const float* p = src + off;
  st8(*reinterpret_cast<const float4*>(p),
      *reinterpret_cast<const float4*>(p + 4), dst);
}

// C[M,N](ldc) = A[M,K](lda) * B[N,K](ldb)^T (+bias)(+relu). K mult of BK.
// Dual-operand batching: staged A row r uses (r < Msplit ? A : A2) at local
// row (r - Msplit); B and row-selected bias per block row: bm<Msplit?B:B2.
// BIAS_COL: bp[gc]. BIAS_COL2: gc<colsplit ? bias[gc] : bias2[gc-colsplit].
// BIAS_ROW: bp[gr & rowmask].
// A_RAW/B_RAW: f32 source, global->reg prefetch at loop top, cvt+ds_write
// after MFMA; bf16 source staged via global_load_lds (issued at loop top).
// Double-buffered LDS, one barrier per BK-step. BK=64 = two 32-wide
// subtiles, half-major LDS layout (all swizzle math per 32-subtile).
// LDS 16B-chunk XOR-swizzled with (row>>1)&3 (linear dest + pre-swizzled
// source column + swizzled read) -> 0 bank conflicts (verified r1).
// Wave maps: NT=512: 8 waves 4x2 of 32x64 (TM=TN=128, 32KB LDS). NT=256:
// 128x128 -> 2x2 waves of 64x64 (m97 shape, 16 MFMA : 8 ds_read per
// wave-step -- best ratio); 128x64 -> 4x1 of 32x64; 64x64 -> 2x2 of 32x32.
// LB = launch-bounds min-waves/EU (r5: this is the occupancy cap; raise to
// the LDS/VGPR limit) -- BUT (r8 lesson) only when the concurrent L2
// working set still fits: 8 resident blocks of a B-panel-reuse GEMM
// turned F memory-bound (FETCH 49->130 MB). Latency regime otherwise:
// waves-in-flight dominate (r1/r2/r4).
template <typename OutT, int BIAS, bool RELU, bool A_RAW, bool B_RAW, int TM,
          int TN, int BK, int NT, int LB>
__global__ __launch_bounds__(NT, LB) void gemm_db(
    const void* __restrict__ A, const void* __restrict__ A2,
    const void* __restrict__ B, const void* __restrict__ B2,
    const float* __restrict__ bias, const float* __restrict__ bias2,
    OutT* __restrict__ C, int M, int N, int K, int lda, int ldb, int MA,
    int NB, int ldc, int Msplit, int rowmask, int colsplit) {
  constexpr int SA = (TM * BK) / (NT * 8);  // A staging slots
  constexpr int SB = (TN * BK) / (NT * 8);
  constexpr int AI = (NT == 512) ? 2 : ((TM == 128 && TN == 128) ? 4 : 2);
  constexpr int BJ = (TM == 64 && TN == 64) ? 2 : 4;
  __shared__ __align__(16) u16 As[2][TM * BK];
  __shared__ __align__(16) u16 Bs[2][TN * BK];
  const int tid = threadIdx.x;
  const int lane = tid & 63;
  const int wv = tid >> 6;
  int wr, wc;
  if constexpr (NT == 512) {
    wr = (wv & 3) * 32; wc = (wv >> 2) * 64;
  } else if constexpr (TM == 128 && TN == 128) {
    wr = (wv >> 1) * 64; wc = (wv & 1) * 64;
  } else if constexpr (TM == 128 && TN == 64) {
    wr = wv * 32; wc = 0;
  } else {
    wr = (wv >> 1) * 32; wc = (wv & 1) * 32;
  }
  const int mrow = lane & 15;
  const int quad = lane >> 4;

  // Bijective XCD swizzle (all grids here are %8==0; identity otherwise).
  int bxi = blockIdx.x, byi = blockIdx.y;
  {
    const int gx = (int)gridDim.x;
    const int nwg = gx * (int)gridDim.y;
    if ((nwg & 7) == 0) {
      int wg = byi * gx + bxi;
      wg = (wg & 7) * (nwg >> 3) + (wg >> 3);
      bxi = wg % gx;
      byi = wg / gx;
    }
  }
  const int bm = byi * TM;
  const int bn = bxi * TN;

  f32x4 acc[AI][BJ];
#pragma unroll
  for (int i = 0; i < AI; i++)
#pragma unroll
    for (int j = 0; j < BJ; j++) acc[i][j] = f32x4{0.f, 0.f, 0.f, 0.f};

  // Staging: NT threads x 8 elems (16B) per slot; half-major linear LDS.
  // Slot s covers elems [s*NT*8, (s+1)*NT*8) of (half, row, col32) order.
  const int e0 = tid * 8;
  const int r0t = e0 >> 5;  // row within slot row-span
  const int swc8 = ((((e0 >> 3) & 3) ^ ((r0t >> 1) & 3)) << 3);

  const void* Asrc[SA];
  size_t aoff[SA];
#pragma unroll
  for (int s = 0; s < SA; s++) {
    const int h = (s * NT * 8) / (TM * 32);
    const int rb = ((s * NT * 8) % (TM * 32)) >> 5;
    int ra = bm + rb + r0t;
    if (ra >= MA) ra = MA - 1;
    Asrc[s] = (ra < Msplit) ? A : A2;
    const int rr = (ra < Msplit) ? ra : ra - Msplit;
    aoff[s] = (size_t)rr * lda + h * 32 + swc8;
  }
  const void* Bb = (bm < Msplit) ? B : B2;
  size_t boff[SB];
#pragma unroll
  for (int s = 0; s < SB; s++) {
    const int h = (s * NT * 8) / (TN * 32);
    const int rb = ((s * NT * 8) % (TN * 32)) >> 5;
    int rbn = bn + rb + r0t;
    if (rbn >= NB) rbn = NB - 1;
    boff[s] = (size_t)rbn * ldb + h * 32 + swc8;
  }

  // ---- prologue: stage k=0 into buffer 0
#pragma unroll
  for (int s = 0; s < SA; s++) {
    if constexpr (A_RAW) {
      const float* p = (const float*)Asrc[s] + aoff[s];
      st8(*reinterpret_cast<const float4*>(p),
          *reinterpret_cast<const float4*>(p + 4), &As[0][s * NT * 8 + e0]);
    } else {
      gld_lds16((const u16*)Asrc[s] + aoff[s], &As[0][s * NT * 8 + e0]);
    }
  }
#pragma unroll
  for (int s = 0; s < SB; s++) {
    if constexpr (B_RAW) {
      const float* p = (const float*)Bb + boff[s];
      st8(*reinterpret_cast<const float4*>(p),
          *reinterpret_cast<const float4*>(p + 4), &Bs[0][s * NT * 8 + e0]);
    } else {
      gld_lds16((const u16*)Bb + boff[s], &Bs[0][s * NT * 8 + e0]);
    }
  }
  __syncthreads();

  // Read-side swizzle: chunk quad of row (16a+mrow) is at quad^((mrow>>1)&3).
  const int so = ((quad ^ ((mrow >> 1) & 3)) << 3);

  int cur = 0;
  for (int k0 = 0; k0 < K; k0 += BK) {
    const int nk = k0 + BK;
    const bool pf = nk < K;
    float4 fA[SA][2], fB[SB][2];
    if (pf) {
#pragma unroll
      for (int s = 0; s < SA; s++) {
        if constexpr (A_RAW) {
          const float* p = (const float*)Asrc[s] + aoff[s] + nk;
          fA[s][0] = *reinterpret_cast<const float4*>(p);
          fA[s][1] = *reinterpret_cast<const float4*>(p + 4);
        } else {
          gld_lds16((const u16*)Asrc[s] + aoff[s] + nk,
                    &As[cur ^ 1][s * NT * 8 + e0]);
        }
      }
#pragma unroll
      for (int s = 0; s < SB; s++) {
        if constexpr (B_RAW) {
          const float* p = (const float*)Bb + boff[s] + nk;
          fB[s][0] = *reinterpret_cast<const float4*>(p);
          fB[s][1] = *reinterpret_cast<const float4*>(p + 4);
        } else {
          gld_lds16((const u16*)Bb + boff[s] + nk,
                    &Bs[cur ^ 1][s * NT * 8 + e0]);
        }
      }
    }
    // compute on buffer `cur` (BK/32 halves)
#pragma unroll
    for (int h = 0; h < BK / 32; h++) {
      bf16x8 af[AI], bfm[BJ];
#pragma unroll
      for (int i = 0; i < AI; i++)
        af[i] = *reinterpret_cast<const bf16x8*>(
            &As[cur][h * TM * 32 + (wr + i * 16 + mrow) * 32 + so]);
#pragma unroll
      for (int j = 0; j < BJ; j++)
        bfm[j] = *reinterpret_cast<const bf16x8*>(
            &Bs[cur][h * TN * 32 + (wc + j * 16 + mrow) * 32 + so]);
#pragma unroll
      for (int i = 0; i < AI; i++)
#pragma unroll
        for (int j = 0; j < BJ; j++)
          acc[i][j] = __builtin_amdgcn_mfma_f32_16x16x32_bf16(
              af[i], bfm[j], acc[i][j], 0, 0, 0);
    }
    // late half of RAW staging: cvt + ds_write into next buffer
    if (pf) {
      if constexpr (A_RAW) {
#pragma unroll
        for (int s = 0; s < SA; s++)
          st8(fA[s][0], fA[s][1], &As[cur ^ 1][s * NT * 8 + e0]);
      }
      if constexpr (B_RAW) {
#pragma unroll
        for (int s = 0; s < SB; s++)
          st8(fB[s][0], fB[s][1], &Bs[cur ^ 1][s * NT * 8 + e0]);
      }
    }
    __syncthreads();
    cur ^= 1;
  }

  const float* bp = (bm < Msplit) ? bias : bias2;
#pragma unroll
  for (int i = 0; i < AI; i++) {
#pragma unroll
    for (int j = 0; j < BJ; j++) {
#pragma unroll
      for (int r = 0; r < 4; r++) {
        const int gr = bm + wr + i * 16 + quad * 4 + r;
        const int gc = bn + wc + j * 16 + mrow;
        if (gr < M && gc < N) {
          float v = acc[i][j][r];
          if (BIAS == BIAS_COL) v += bp[gc];
          if (BIAS == BIAS_COL2)
            v += (gc < colsplit) ? bias[gc] : bias2[gc - colsplit];
          if (BIAS == BIAS_ROW) v += bp[gr & rowmask];
          if (RELU) v = fmaxf(v, 0.f);
          if constexpr (std::is_same<OutT, float>::value)
            C[(size_t)gr * ldc + gc] = v;
          else
            C[(size_t)gr * ldc + gc] = f2b(v);
        }
      }
    }
  }
}

// Up-to-3-segment f32 -> bf16 bulk conversion; blocksPer blocks/segment,
// each segment exactly blocksPer*256*8 elems.
__global__ __launch_bounds__(256) void cvt3_k(
    const float* __restrict__ s0, u16* __restrict__ d0,
    const float* __restrict__ s1, u16* __restrict__ d1,
    const float* __restrict__ s2, u16* __restrict__ d2, int blocksPer) {
  const int seg = blockIdx.x / blocksPer;
  const int b = blockIdx.x % blocksPer;
  const float* s = (seg == 0) ? s0 : ((seg == 1) ? s1 : s2);
  u16* d = (seg == 0) ? d0 : ((seg == 1) ? d1 : d2);
  const size_t i = ((size_t)b * 256 + threadIdx.x) * 8;
  stage8_cvt(s, i, d + i);
}

// Transposed bf16 conversion: dst[d][j] = bf16(src[j][d]), 1024x1024.
__global__ __launch_bounds__(256) void wqt_k(const float* __restrict__ src,
                                             u16* __restrict__ dst) {
  __shared__ float t[64][65];
  const int bx = blockIdx.x;  // d-tile
  const int by = blockIdx.y;  // j-tile
  const int tx = threadIdx.x & 63;
  const int ty = threadIdx.x >> 6;
#pragma unroll
  for (int i = 0; i < 16; i++)
    t[ty * 16 + i][tx] =
        src[(size_t)(by * 64 + ty * 16 + i) * 1024 + bx * 64 + tx];
  __syncthreads();
#pragma unroll
  for (int i = 0; i < 16; i++)
    dst[(size_t)(bx * 64 + ty * 16 + i) * 1024 + by * 64 + tx] =
        f2b(t[tx][ty * 16 + i]);
}

// kb[b*224+s] = sum_j bf16(Kc[(b*196+s)*ld + j]) * bq[j] (s<196; else 0).
__global__ __launch_bounds__(256) void kb_k(const u16* __restrict__ Kc,
                                            const float* __restrict__ bq,
                                            float* __restrict__ kb, int ld) {
  const int wvi = blockIdx.x * 4 + (threadIdx.x >> 6);  // 0..447
  const int lane = threadIdx.x & 63;
  const int b = wvi / 224, s = wvi % 224;
  float sum = 0.f;
  if (s < 196) {
    const u16* row = Kc + (size_t)(b * 196 + s) * ld;
    for (int j = lane; j < 1024; j += 64) sum += b2f(row[j]) * bq[j];
  }
#pragma unroll
  for (int off = 32; off > 0; off >>= 1) sum += __shfl_xor(sum, off);
  if (lane == 0) kb[wvi] = sum;
}

// In-place softmax over Sp[row, 0..224) bf16 (16384 batched rows):
// p = softmax((s + score)/8) over cols < 196; cols 196..223 zeroed.
__global__ __launch_bounds__(256) void softmax_k(
    u16* __restrict__ Sp, const float* __restrict__ sc1,
    const float* __restrict__ sc2) {
  const int row = blockIdx.x * 4 + (threadIdx.x >> 6);
  const int lane = threadIdx.x & 63;
  const float* score = (row < 8192) ? sc1 + (size_t)row * 196
                                    : sc2 + (size_t)(row - 8192) * 196;
  float x[4];
  float mx = -1e30f;
#pragma unroll
  for (int t = 0; t < 4; t++) {
    const int s = lane + 64 * t;
    float v = -1e30f;
    if (s < 196) v = (b2f(Sp[(size_t)row * 224 + s]) + score[s]) * 0.125f;
    x[t] = v;
    mx = fmaxf(mx, v);
  }
#pragma unroll
  for (int off = 32; off > 0; off >>= 1) mx = fmaxf(mx, __shfl_xor(mx, off));
  float sum = 0.f;
#pragma unroll
  for (int t = 0; t < 4; t++) {
    const int s = lane + 64 * t;
    const float e = (s < 196) ? expf(x[t] - mx) : 0.f;
    x[t] = e;
    sum += e;
  }
#pragma unroll
  for (int off = 32; off > 0; off >>= 1) sum += __shfl_xor(sum, off);
  const float inv = 1.f / sum;
#pragma unroll
  for (int t = 0; t < 4; t++) {
    const int s = lane + 64 * t;
    if (s < 224) Sp[(size_t)row * 224 + s] = f2b((s < 196) ? x[t] * inv : 0.f);
  }
}

// Fused both-branch residual-LN-pool: block row16 in [0,16384);
// branch = row16>>13 selects text/colbase. t = LN(X + Y)*g + be (D=1024);
// pooled[row, colbase+i] = max(t[2i], t[2i+1]).
__global__ __launch_bounds__(256) void ln_pool_k(
    const float* __restrict__ X1, const float* __restrict__ X2,
    const u16* __restrict__ Y, const float* __restrict__ g,
    const float* __restrict__ be, u16* __restrict__ pooled) {
  const int row16 = blockIdx.x;
  const int br = row16 >> 13;
  const int row = row16 & 8191;
  const int tid = threadIdx.x;
  const int lane = tid & 63;
  const int wv = tid >> 6;
  const float* X = (br ? X2 : X1) + (size_t)row * 1024;
  const u16* Yp = Y + (size_t)row16 * 1024;
  __shared__ float red[4];
  float v[4];
  float s = 0.f;
#pragma unroll
  for (int j = 0; j < 4; j++) {
    const float a = X[tid * 4 + j] + b2f(Yp[tid * 4 + j]);
    v[j] = a;
    s += a;
  }
#pragma unroll
  for (int off = 32; off > 0; off >>= 1) s += __shfl_xor(s, off);
  if (lane == 0) red[wv] = s;
  __syncthreads();
  const float mu = (red[0] + red[1] + red[2] + red[3]) * (1.f / 1024.f);
  __syncthreads();
  float var = 0.f;
#pragma unroll
  for (int j = 0; j < 4; j++) {
    const float d = v[j] - mu;
    var += d * d;
  }
#pragma unroll
  for (int off = 32; off > 0; off >>= 1) var += __shfl_xor(var, off);
  if (lane == 0) red[wv] = var;
  __syncthreads();
  var = (red[0] + red[1] + red[2] + red[3]) * (1.f / 1024.f);
  const float rs = rsqrtf(var + LN_EPS);
  float n[4];
#pragma unroll
  for (int j = 0; j < 4; j++)
    n[j] = (v[j] - mu) * rs * g[tid * 4 + j] + be[tid * 4 + j];
  const size_t pb = (size_t)row * 1024 + br * 512 + tid * 2;
  pooled[pb] = f2b(fmaxf(n[0], n[1]));
  pooled[pb + 1] = f2b(fmaxf(n[2], n[3]));
}

// out(f32) = LN(X(bf16) + Y(bf16))*g + be over D=1024.
__global__ __launch_bounds__(256) void ln_out_k(
    const u16* __restrict__ X, const u16* __restrict__ Y,
    const float* __restrict__ g, const float* __restrict__ be,
    float* __restrict__ out) {
  const int row = blockIdx.x;
  const int tid = threadIdx.x;
  const int lane = tid & 63;
  const int wv = tid >> 6;
  __shared__ float red[4];
  float v[4];
  float s = 0.f;
  const size_t base = (size_t)row * 1024 + tid * 4;
#pragma unroll
  for (int j = 0; j < 4; j++) {
    const float a = b2f(X[base + j]) + b2f(Y[base + j]);
    v[j] = a;
    s += a;
  }
#pragma unroll
  for (int off = 32; off > 0; off >>= 1) s += __shfl_xor(s, off);
  if (lane == 0) red[wv] = s;
  __syncthreads();
  const float mu = (red[0] + red[1] + red[2] + red[3]) * (1.f / 1024.f);
  __syncthreads();
  float var = 0.f;
#pragma unroll
  for (int j = 0; j < 4; j++) {
    const float d = v[j] - mu;
    var += d * d;
  }
#pragma unroll
  for (int off = 32; off > 0; off >>= 1) var += __shfl_xor(var, off);
  if (lane == 0) red[wv] = var;
  __syncthreads();
  var = (red[0] + red[1] + red[2] + red[3]) * (1.f / 1024.f);
  const float rs = rsqrtf(var + LN_EPS);
#pragma unroll
  for (int j = 0; j < 4; j++)
    out[base + j] = (v[j] - mu) * rs * g[tid * 4 + j] + be[tid * 4 + j];
}

extern "C" void kernel_launch(void* const* d_in, const int* in_sizes, int n_in,
                              void* d_out, int out_size, void* d_ws,
                              size_t ws_size, hipStream_t stream) {
  const size_t MB = 1ull << 20;
  if (ws_size < 61 * MB) return;  // proven >= 61 MiB

  const float* text1 = (const float*)d_in[0];
  const float* vis1 = (const float*)d_in[1];
  const float* sc1 = (const float*)d_in[2];
  const float* text2 = (const float*)d_in[3];
  const float* vis2 = (const float*)d_in[4];
  const float* sc2 = (const float*)d_in[5];
  const float* Wq = (const float*)d_in[6];
  const float* bq = (const float*)d_in[7];
  const float* Wk = (const float*)d_in[8];
  const float* bk = (const float*)d_in[9];
  const float* Wv = (const float*)d_in[10];
  const float* bv = (const float*)d_in[11];
  const float* Wo = (const float*)d_in[12];
  const float* bo = (const float*)d_in[13];
  const float* W1 = (const float*)d_in[14];
  const float* b1 = (const float*)d_in[15];
  const float* W2 = (const float*)d_in[16];
  const float* b2 = (const float*)d_in[17];
  const float* g1 = (const float*)d_in[18];
  const float* be1 = (const float*)d_in[19];
  const float* g2 = (const float*)d_in[20];
  const float* be2 = (const float*)d_in[21];

  const int D = 1024, Sv = 196, SvP = 224, DFF = 4096;
  const int M2 = 16384;
  char* w = (char*)d_ws;
  // Algebra (r4): S = text·(K·Wq)^T + (K·bq)^T ; O = P·(V·Wo^T+1·bo^T)^T.
  // FFN (r7 structure, reverted from r8's split-K regression): row-chunked
  // H [4096,4096] bf16; F 64x64/BK64 with bf16 W2; W1 read RAW f32 in H
  // (r8-verified path; drops half the FFN weight conversion).
  // ws layout (peak 56 MiB <= proven 61):
  //  [0,16)  pooled bf16 [8192,1024] (persists)
  //  [16,18) Wkb [18,20) Wvb (contiguous: stacked B for KVcat GEMM)
  //  [20,22) Wob [22,24) WqT
  //  [24,..) KVcat [392,2048] 1.53M  [26,..) K2cat [392,1024] 784K
  //  [27,..) VWoT [2048,224] 896K    [28,..) kb f32[448]
  //  [29,36) Spcat bf16 [16384,224] 7 MB
  //  Ocat: d_out (32 MB bf16 scratch; dead until ln_out rewrites it)
  //  Phase B: [16,48) H bf16 [4096,4096]  [48,56) F bf16 [4096,1024]
  //           W2b in d_out[16,24) MB (dead after ln_pool until
  //           ln_out(c=1), which runs after F(c=1), the last consumer).
  u16* pooled = (u16*)(w + 0 * MB);
  u16* Wkb = (u16*)(w + 16 * MB);  // KVcat B-panel = Wkb..Wvb stacked
  u16* Wvb = (u16*)(w + 18 * MB);
  u16* Wob = (u16*)(w + 20 * MB);
  u16* WqT = (u16*)(w + 22 * MB);
  u16* KVcat = (u16*)(w + 24 * MB);
  u16* K2cat = (u16*)(w + 26 * MB);
  u16* VWoT = (u16*)(w + 27 * MB);
  float* kb = (float*)(w + 28 * MB);
  u16* Spcat = (u16*)(w + 29 * MB);
  u16* Ocat = (u16*)d_out;
  u16* H = (u16*)(w + 16 * MB);
  u16* F = (u16*)(w + 48 * MB);
  u16* W2b = (u16*)((char*)d_out + 16 * MB);

  auto grid = [](int m, int n, int tm, int tn) {
    return dim3((unsigned)((n + tn - 1) / tn), (unsigned)((m + tm - 1) / tm));
  };

  // Attention weights to bf16: Wk/Wv/Wo fused (512 blocks each); Wq
  // transposed (needed as K·Wq).
  cvt3_k<<<dim3(3 * 512), 256, 0, stream>>>(Wk, Wkb, Wv, Wvb, Wo, Wob, 512);
  wqt_k<<<dim3(16, 16), 256, 0, stream>>>(Wq, WqT);

  // KVcat[392,2048] = [vis1;vis2](raw f32) @ [Wk;Wv]^T + [bk|bv]
  gemm_db<u16, BIAS_COL2, false, true, false, 64, 64, 32, 256, 8>
      <<<grid(2 * Sv, 2 * D, 64, 64), 256, 0, stream>>>(
          vis1, vis2, Wkb, Wkb, bk, bv, KVcat, 2 * Sv, 2 * D, D, D, D, 2 * Sv,
          2 * D, 2 * D, Sv, 0, D);
  // K2cat[392,1024] = Kcat(lda=2048) @ Wq
  gemm_db<u16, BIAS_NONE, false, false, false, 64, 64, 32, 256, 8>
      <<<grid(2 * Sv, D, 64, 64), 256, 0, stream>>>(
          KVcat, KVcat, WqT, WqT, nullptr, nullptr, K2cat, 2 * Sv, D, D, 2 * D,
          D, 2 * Sv, D, D, 2 * Sv, 0, 0);
  // kb[2][224] = Kcat · bq
  kb_k<<<dim3(112), 256, 0, stream>>>(KVcat, bq, kb, 2 * D);
  // Spcat[16384,ldc=224] = textcat(raw f32) @ K2_br^T + kb_br (row-half)
  gemm_db<u16, BIAS_COL, false, true, false, 64, 64, 32, 256, 8>
      <<<grid(M2, Sv, 64, 64), 256, 0, stream>>>(
          text1, text2, K2cat, K2cat + (size_t)Sv * D, kb, kb + SvP, Spcat, M2,
          Sv, D, D, D, M2, Sv, SvP, 8192, 0, 0);
  // softmax((Sp + score)/8), pad zeros
  softmax_k<<<dim3(M2 / 4), 256, 0, stream>>>(Spcat, sc1, sc2);
  // VWoT[2048,224]: row b*1024+n = Wo[n]·V_br[s] + bo[n]
  gemm_db<u16, BIAS_ROW, false, false, false, 64, 64, 32, 256, 8>
      <<<grid(2 * D, SvP, 64, 64), 256, 0, stream>>>(
          Wob, Wob, KVcat + D, KVcat + (size_t)Sv * 2 * D + D, bo, bo, VWoT,
          2 * D, SvP, D, D, 2 * D, 2 * D, Sv, SvP, D, D - 1, 0);
  // Ocat[16384,1024] = Spcat @ VWoT_br^T, K=224 (d_out scratch) -- 4096 blk
  gemm_db<u16, BIAS_NONE, false, false, false, 64, 64, 32, 256, 8>
      <<<grid(M2, D, 64, 64), 256, 0, stream>>>(
          Spcat, Spcat + (size_t)8192 * SvP, VWoT, VWoT + (size_t)D * SvP,
          nullptr, nullptr, Ocat, M2, D, SvP, SvP, SvP, M2, D, D, 8192, 0, 0);
  // fused both-branch residual + LN + maxpool -> pooled
  ln_pool_k<<<dim3(M2), 256, 0, stream>>>(text1, text2, Ocat, g1, be1, pooled);

  // W2 to bf16 (d_out[16,24) is dead scratch now); W1 stays raw f32.
  cvt3_k<<<dim3(2048), 256, 0, stream>>>(W2, W2b, W2, W2b, W2, W2b, 2048);

  // FFN in 2 row-chunks of 4096 (r7 structure).
  for (int c = 0; c < 2; ++c) {
    const int r0 = c * 4096, rows = 4096;
    // H = relu(pooled_c @ W1^T + b1) -- m97 shape: NT=256 128x128
    // (16 MFMA : 8 ds_read per wave-step), LB=4, grid (32,32); W1 raw f32.
    gemm_db<u16, BIAS_COL, true, false, true, 128, 128, 32, 256, 4>
        <<<grid(rows, DFF, 128, 128), 256, 0, stream>>>(
            pooled + (size_t)r0 * D, pooled + (size_t)r0 * D, W1, W1, b1, b1,
            H, rows, DFF, D, D, D, rows, DFF, DFF, rows, 0, 0);
    // F = H @ W2b^T + b2 -- 64x64 BK=64 (32KB LDS), lb=5 (LDS cap)
    gemm_db<u16, BIAS_COL, false, false, false, 64, 64, 64, 256, 5>
        <<<grid(rows, D, 64, 64), 256, 0, stream>>>(
            H, H, W2b, W2b, b2, b2, F, rows, D, DFF, DFF, DFF, rows, D, D,
            rows, 0, 0);
    // out_c = LN(pooled_c + F)  f32
    ln_out_k<<<dim3(rows), 256, 0, stream>>>(
        pooled + (size_t)r0 * D, F, g2, be2, (float*)d_out + (size_t)r0 * D);
  }
}

// Round 10
// 538.818 us; speedup vs baseline: 1.1810x; 1.0330x over previous
//
#include <hip/hip_runtime.h>
#include <hip/hip_bf16.h>
#include <cstdint>
#include <type_traits>

typedef unsigned short u16;
typedef __bf16 bf16x8 __attribute__((ext_vector_type(8)));
typedef float f32x4 __attribute__((ext_vector_type(4)));

#define LN_EPS 1e-6f

enum { BIAS_NONE = 0, BIAS_COL = 1, BIAS_ROW = 2, BIAS_COL2 = 3 };

__device__ __forceinline__ float b2f(u16 h) {
  union { unsigned u; float f; } v;
  v.u = ((unsigned)h) << 16;
  return v.f;
}
__device__ __forceinline__ u16 f2b(float x) {
  return __bfloat16_as_ushort(__float2bfloat16(x));
}

__device__ __forceinline__ void gld_lds16(const void* g, void* l) {
  __builtin_amdgcn_global_load_lds(
      (const __attribute__((address_space(1))) void*)g,
      (__attribute__((address_space(3))) void*)l, 16, 0, 0);
}

// 8x f32 -> 8x bf16, one 16B store.
__device__ __forceinline__ void st8(float4 a, float4 b, u16* dst) {
  u16 t[8] = {f2b(a.x), f2b(a.y), f2b(a.z), f2b(a.w),
              f2b(b.x), f2b(b.y), f2b(b.z), f2b(b.w)};
  *reinterpret_cast<uint4*>(dst) = *reinterpret_cast<const uint4*>(t);
}

__device__ __forceinline__ void stage8_cvt(const float* src, size_t off,
                                           u16* dst) {
  const float* p = src + off;
  st8(*reinterpret_cast<const float4*>(p),
      *reinterpret_cast<const float4*>(p + 4), dst);
}

// C[M,N](ldc) = A[M,K](lda) * B[N,K](ldb)^T (+bias)(+relu). K mult of BK.
// Dual-operand batching: staged A row r uses (r < Msplit ? A : A2) at local
// row (r - Msplit); B and row-selected bias per block row: bm<Msplit?B:B2.
// BIAS_COL: bp[gc]. BIAS_COL2: gc<colsplit ? bias[gc] : bias2[gc-colsplit].
// BIAS_ROW: bp[gr & rowmask].
// A_RAW/B_RAW: f32 source, global->reg prefetch at loop top, cvt+ds_write
// after MFMA; bf16 source staged via global_load_lds (issued at loop top).
// RAW is ONLY for streamed-once A-panels (r9 lesson: raw W1 in H cost
// +20us/dispatch -- reused B-panels must be pre-converted to bf16).
// Double-buffered LDS, one barrier per BK-step. BK=64 = two 32-wide
// subtiles, half-major LDS layout (all swizzle math per 32-subtile).
// LDS 16B-chunk XOR-swizzled with (row>>1)&3 (linear dest + pre-swizzled
// source column + swizzled read) -> 0 bank conflicts (verified r1).
// Wave maps: NT=512: 8 waves 4x2 of 32x64 (TM=TN=128, 32KB LDS). NT=256:
// 128x128 -> 2x2 waves of 64x64 (m97 shape, 16 MFMA : 8 ds_read per
// wave-step -- best ratio); 128x64 -> 4x1 of 32x64; 64x64 -> 2x2 of 32x32.
// LB = launch-bounds min-waves/EU (r5: this is the occupancy cap; raise to
// the LDS/VGPR limit) -- BUT (r8 lesson) only when the concurrent L2
// working set still fits: 8 resident blocks of a B-panel-reuse GEMM with
// f32 weights turned F memory-bound (FETCH 49->130 MB). Latency regime
// otherwise: waves-in-flight dominate (r1/r2/r4).
template <typename OutT, int BIAS, bool RELU, bool A_RAW, bool B_RAW, int TM,
          int TN, int BK, int NT, int LB>
__global__ __launch_bounds__(NT, LB) void gemm_db(
    const void* __restrict__ A, const void* __restrict__ A2,
    const void* __restrict__ B, const void* __restrict__ B2,
    const float* __restrict__ bias, const float* __restrict__ bias2,
    OutT* __restrict__ C, int M, int N, int K, int lda, int ldb, int MA,
    int NB, int ldc, int Msplit, int rowmask, int colsplit) {
  constexpr int SA = (TM * BK) / (NT * 8);  // A staging slots
  constexpr int SB = (TN * BK) / (NT * 8);
  constexpr int AI = (NT == 512) ? 2 : ((TM == 128 && TN == 128) ? 4 : 2);
  constexpr int BJ = (TM == 64 && TN == 64) ? 2 : 4;
  __shared__ __align__(16) u16 As[2][TM * BK];
  __shared__ __align__(16) u16 Bs[2][TN * BK];
  const int tid = threadIdx.x;
  const int lane = tid & 63;
  const int wv = tid >> 6;
  int wr, wc;
  if constexpr (NT == 512) {
    wr = (wv & 3) * 32; wc = (wv >> 2) * 64;
  } else if constexpr (TM == 128 && TN == 128) {
    wr = (wv >> 1) * 64; wc = (wv & 1) * 64;
  } else if constexpr (TM == 128 && TN == 64) {
    wr = wv * 32; wc = 0;
  } else {
    wr = (wv >> 1) * 32; wc = (wv & 1) * 32;
  }
  const int mrow = lane & 15;
  const int quad = lane >> 4;

  // Bijective XCD swizzle (all grids here are %8==0; identity otherwise).
  int bxi = blockIdx.x, byi = blockIdx.y;
  {
    const int gx = (int)gridDim.x;
    const int nwg = gx * (int)gridDim.y;
    if ((nwg & 7) == 0) {
      int wg = byi * gx + bxi;
      wg = (wg & 7) * (nwg >> 3) + (wg >> 3);
      bxi = wg % gx;
      byi = wg / gx;
    }
  }
  const int bm = byi * TM;
  const int bn = bxi * TN;

  f32x4 acc[AI][BJ];
#pragma unroll
  for (int i = 0; i < AI; i++)
#pragma unroll
    for (int j = 0; j < BJ; j++) acc[i][j] = f32x4{0.f, 0.f, 0.f, 0.f};

  // Staging: NT threads x 8 elems (16B) per slot; half-major linear LDS.
  // Slot s covers elems [s*NT*8, (s+1)*NT*8) of (half, row, col32) order.
  const int e0 = tid * 8;
  const int r0t = e0 >> 5;  // row within slot row-span
  const int swc8 = ((((e0 >> 3) & 3) ^ ((r0t >> 1) & 3)) << 3);

  const void* Asrc[SA];
  size_t aoff[SA];
#pragma unroll
  for (int s = 0; s < SA; s++) {
    const int h = (s * NT * 8) / (TM * 32);
    const int rb = ((s * NT * 8) % (TM * 32)) >> 5;
    int ra = bm + rb + r0t;
    if (ra >= MA) ra = MA - 1;
    Asrc[s] = (ra < Msplit) ? A : A2;
    const int rr = (ra < Msplit) ? ra : ra - Msplit;
    aoff[s] = (size_t)rr * lda + h * 32 + swc8;
  }
  const void* Bb = (bm < Msplit) ? B : B2;
  size_t boff[SB];
#pragma unroll
  for (int s = 0; s < SB; s++) {
    const int h = (s * NT * 8) / (TN * 32);
    const int rb = ((s * NT * 8) % (TN * 32)) >> 5;
    int rbn = bn + rb + r0t;
    if (rbn >= NB) rbn = NB - 1;
    boff[s] = (size_t)rbn * ldb + h * 32 + swc8;
  }

  // ---- prologue: stage k=0 into buffer 0
#pragma unroll
  for (int s = 0; s < SA; s++) {
    if constexpr (A_RAW) {
      const float* p = (const float*)Asrc[s] + aoff[s];
      st8(*reinterpret_cast<const float4*>(p),
          *reinterpret_cast<const float4*>(p + 4), &As[0][s * NT * 8 + e0]);
    } else {
      gld_lds16((const u16*)Asrc[s] + aoff[s], &As[0][s * NT * 8 + e0]);
    }
  }
#pragma unroll
  for (int s = 0; s < SB; s++) {
    if constexpr (B_RAW) {
      const float* p = (const float*)Bb + boff[s];
      st8(*reinterpret_cast<const float4*>(p),
          *reinterpret_cast<const float4*>(p + 4), &Bs[0][s * NT * 8 + e0]);
    } else {
      gld_lds16((const u16*)Bb + boff[s], &Bs[0][s * NT * 8 + e0]);
    }
  }
  __syncthreads();

  // Read-side swizzle: chunk quad of row (16a+mrow) is at quad^((mrow>>1)&3).
  const int so = ((quad ^ ((mrow >> 1) & 3)) << 3);

  int cur = 0;
  for (int k0 = 0; k0 < K; k0 += BK) {
    const int nk = k0 + BK;
    const bool pf = nk < K;
    float4 fA[SA][2], fB[SB][2];
    if (pf) {
#pragma unroll
      for (int s = 0; s < SA; s++) {
        if constexpr (A_RAW) {
          const float* p = (const float*)Asrc[s] + aoff[s] + nk;
          fA[s][0] = *reinterpret_cast<const float4*>(p);
          fA[s][1] = *reinterpret_cast<const float4*>(p + 4);
        } else {
          gld_lds16((const u16*)Asrc[s] + aoff[s] + nk,
                    &As[cur ^ 1][s * NT * 8 + e0]);
        }
      }
#pragma unroll
      for (int s = 0; s < SB; s++) {
        if constexpr (B_RAW) {
          const float* p = (const float*)Bb + boff[s] + nk;
          fB[s][0] = *reinterpret_cast<const float4*>(p);
          fB[s][1] = *reinterpret_cast<const float4*>(p + 4);
        } else {
          gld_lds16((const u16*)Bb + boff[s] + nk,
                    &Bs[cur ^ 1][s * NT * 8 + e0]);
        }
      }
    }
    // compute on buffer `cur` (BK/32 halves)
#pragma unroll
    for (int h = 0; h < BK / 32; h++) {
      bf16x8 af[AI], bfm[BJ];
#pragma unroll
      for (int i = 0; i < AI; i++)
        af[i] = *reinterpret_cast<const bf16x8*>(
            &As[cur][h * TM * 32 + (wr + i * 16 + mrow) * 32 + so]);
#pragma unroll
      for (int j = 0; j < BJ; j++)
        bfm[j] = *reinterpret_cast<const bf16x8*>(
            &Bs[cur][h * TN * 32 + (wc + j * 16 + mrow) * 32 + so]);
#pragma unroll
      for (int i = 0; i < AI; i++)
#pragma unroll
        for (int j = 0; j < BJ; j++)
          acc[i][j] = __builtin_amdgcn_mfma_f32_16x16x32_bf16(
              af[i], bfm[j], acc[i][j], 0, 0, 0);
    }
    // late half of RAW staging: cvt + ds_write into next buffer
    if (pf) {
      if constexpr (A_RAW) {
#pragma unroll
        for (int s = 0; s < SA; s++)
          st8(fA[s][0], fA[s][1], &As[cur ^ 1][s * NT * 8 + e0]);
      }
      if constexpr (B_RAW) {
#pragma unroll
        for (int s = 0; s < SB; s++)
          st8(fB[s][0], fB[s][1], &Bs[cur ^ 1][s * NT * 8 + e0]);
      }
    }
    __syncthreads();
    cur ^= 1;
  }

  const float* bp = (bm < Msplit) ? bias : bias2;
#pragma unroll
  for (int i = 0; i < AI; i++) {
#pragma unroll
    for (int j = 0; j < BJ; j++) {
#pragma unroll
      for (int r = 0; r < 4; r++) {
        const int gr = bm + wr + i * 16 + quad * 4 + r;
        const int gc = bn + wc + j * 16 + mrow;
        if (gr < M && gc < N) {
          float v = acc[i][j][r];
          if (BIAS == BIAS_COL) v += bp[gc];
          if (BIAS == BIAS_COL2)
            v += (gc < colsplit) ? bias[gc] : bias2[gc - colsplit];
          if (BIAS == BIAS_ROW) v += bp[gr & rowmask];
          if (RELU) v = fmaxf(v, 0.f);
          if constexpr (std::is_same<OutT, float>::value)
            C[(size_t)gr * ldc + gc] = v;
          else
            C[(size_t)gr * ldc + gc] = f2b(v);
        }
      }
    }
  }
}

// Up-to-3-segment f32 -> bf16 bulk conversion; blocksPer blocks/segment,
// each segment exactly blocksPer*256*8 elems.
__global__ __launch_bounds__(256) void cvt3_k(
    const float* __restrict__ s0, u16* __restrict__ d0,
    const float* __restrict__ s1, u16* __restrict__ d1,
    const float* __restrict__ s2, u16* __restrict__ d2, int blocksPer) {
  const int seg = blockIdx.x / blocksPer;
  const int b = blockIdx.x % blocksPer;
  const float* s = (seg == 0) ? s0 : ((seg == 1) ? s1 : s2);
  u16* d = (seg == 0) ? d0 : ((seg == 1) ? d1 : d2);
  const size_t i = ((size_t)b * 256 + threadIdx.x) * 8;
  stage8_cvt(s, i, d + i);
}

// Transposed bf16 conversion: dst[d][j] = bf16(src[j][d]), 1024x1024.
__global__ __launch_bounds__(256) void wqt_k(const float* __restrict__ src,
                                             u16* __restrict__ dst) {
  __shared__ float t[64][65];
  const int bx = blockIdx.x;  // d-tile
  const int by = blockIdx.y;  // j-tile
  const int tx = threadIdx.x & 63;
  const int ty = threadIdx.x >> 6;
#pragma unroll
  for (int i = 0; i < 16; i++)
    t[ty * 16 + i][tx] =
        src[(size_t)(by * 64 + ty * 16 + i) * 1024 + bx * 64 + tx];
  __syncthreads();
#pragma unroll
  for (int i = 0; i < 16; i++)
    dst[(size_t)(bx * 64 + ty * 16 + i) * 1024 + by * 64 + tx] =
        f2b(t[tx][ty * 16 + i]);
}

// kb[b*224+s] = sum_j bf16(Kc[(b*196+s)*ld + j]) * bq[j] (s<196; else 0).
__global__ __launch_bounds__(256) void kb_k(const u16* __restrict__ Kc,
                                            const float* __restrict__ bq,
                                            float* __restrict__ kb, int ld) {
  const int wvi = blockIdx.x * 4 + (threadIdx.x >> 6);  // 0..447
  const int lane = threadIdx.x & 63;
  const int b = wvi / 224, s = wvi % 224;
  float sum = 0.f;
  if (s < 196) {
    const u16* row = Kc + (size_t)(b * 196 + s) * ld;
    for (int j = lane; j < 1024; j += 64) sum += b2f(row[j]) * bq[j];
  }
#pragma unroll
  for (int off = 32; off > 0; off >>= 1) sum += __shfl_xor(sum, off);
  if (lane == 0) kb[wvi] = sum;
}

// In-place softmax over Sp[row, 0..224) bf16 (16384 batched rows):
// p = softmax((s + score)/8) over cols < 196; cols 196..223 zeroed.
__global__ __launch_bounds__(256) void softmax_k(
    u16* __restrict__ Sp, const float* __restrict__ sc1,
    const float* __restrict__ sc2) {
  const int row = blockIdx.x * 4 + (threadIdx.x >> 6);
  const int lane = threadIdx.x & 63;
  const float* score = (row < 8192) ? sc1 + (size_t)row * 196
                                    : sc2 + (size_t)(row - 8192) * 196;
  float x[4];
  float mx = -1e30f;
#pragma unroll
  for (int t = 0; t < 4; t++) {
    const int s = lane + 64 * t;
    float v = -1e30f;
    if (s < 196) v = (b2f(Sp[(size_t)row * 224 + s]) + score[s]) * 0.125f;
    x[t] = v;
    mx = fmaxf(mx, v);
  }
#pragma unroll
  for (int off = 32; off > 0; off >>= 1) mx = fmaxf(mx, __shfl_xor(mx, off));
  float sum = 0.f;
#pragma unroll
  for (int t = 0; t < 4; t++) {
    const int s = lane + 64 * t;
    const float e = (s < 196) ? expf(x[t] - mx) : 0.f;
    x[t] = e;
    sum += e;
  }
#pragma unroll
  for (int off = 32; off > 0; off >>= 1) sum += __shfl_xor(sum, off);
  const float inv = 1.f / sum;
#pragma unroll
  for (int t = 0; t < 4; t++) {
    const int s = lane + 64 * t;
    if (s < 224) Sp[(size_t)row * 224 + s] = f2b((s < 196) ? x[t] * inv : 0.f);
  }
}

// Fused both-branch residual-LN-pool: block row16 in [0,16384);
// branch = row16>>13 selects text/colbase. t = LN(X + Y)*g + be (D=1024);
// pooled[row, colbase+i] = max(t[2i], t[2i+1]).
__global__ __launch_bounds__(256) void ln_pool_k(
    const float* __restrict__ X1, const float* __restrict__ X2,
    const u16* __restrict__ Y, const float* __restrict__ g,
    const float* __restrict__ be, u16* __restrict__ pooled) {
  const int row16 = blockIdx.x;
  const int br = row16 >> 13;
  const int row = row16 & 8191;
  const int tid = threadIdx.x;
  const int lane = tid & 63;
  const int wv = tid >> 6;
  const float* X = (br ? X2 : X1) + (size_t)row * 1024;
  const u16* Yp = Y + (size_t)row16 * 1024;
  __shared__ float red[4];
  float v[4];
  float s = 0.f;
#pragma unroll
  for (int j = 0; j < 4; j++) {
    const float a = X[tid * 4 + j] + b2f(Yp[tid * 4 + j]);
    v[j] = a;
    s += a;
  }
#pragma unroll
  for (int off = 32; off > 0; off >>= 1) s += __shfl_xor(s, off);
  if (lane == 0) red[wv] = s;
  __syncthreads();
  const float mu = (red[0] + red[1] + red[2] + red[3]) * (1.f / 1024.f);
  __syncthreads();
  float var = 0.f;
#pragma unroll
  for (int j = 0; j < 4; j++) {
    const float d = v[j] - mu;
    var += d * d;
  }
#pragma unroll
  for (int off = 32; off > 0; off >>= 1) var += __shfl_xor(var, off);
  if (lane == 0) red[wv] = var;
  __syncthreads();
  var = (red[0] + red[1] + red[2] + red[3]) * (1.f / 1024.f);
  const float rs = rsqrtf(var + LN_EPS);
  float n[4];
#pragma unroll
  for (int j = 0; j < 4; j++)
    n[j] = (v[j] - mu) * rs * g[tid * 4 + j] + be[tid * 4 + j];
  const size_t pb = (size_t)row * 1024 + br * 512 + tid * 2;
  pooled[pb] = f2b(fmaxf(n[0], n[1]));
  pooled[pb + 1] = f2b(fmaxf(n[2], n[3]));
}

// out(f32) = LN(X(bf16) + Y(bf16))*g + be over D=1024.
__global__ __launch_bounds__(256) void ln_out_k(
    const u16* __restrict__ X, const u16* __restrict__ Y,
    const float* __restrict__ g, const float* __restrict__ be,
    float* __restrict__ out) {
  const int row = blockIdx.x;
  const int tid = threadIdx.x;
  const int lane = tid & 63;
  const int wv = tid >> 6;
  __shared__ float red[4];
  float v[4];
  float s = 0.f;
  const size_t base = (size_t)row * 1024 + tid * 4;
#pragma unroll
  for (int j = 0; j < 4; j++) {
    const float a = b2f(X[base + j]) + b2f(Y[base + j]);
    v[j] = a;
    s += a;
  }
#pragma unroll
  for (int off = 32; off > 0; off >>= 1) s += __shfl_xor(s, off);
  if (lane == 0) red[wv] = s;
  __syncthreads();
  const float mu = (red[0] + red[1] + red[2] + red[3]) * (1.f / 1024.f);
  __syncthreads();
  float var = 0.f;
#pragma unroll
  for (int j = 0; j < 4; j++) {
    const float d = v[j] - mu;
    var += d * d;
  }
#pragma unroll
  for (int off = 32; off > 0; off >>= 1) var += __shfl_xor(var, off);
  if (lane == 0) red[wv] = var;
  __syncthreads();
  var = (red[0] + red[1] + red[2] + red[3]) * (1.f / 1024.f);
  const float rs = rsqrtf(var + LN_EPS);
#pragma unroll
  for (int j = 0; j < 4; j++)
    out[base + j] = (v[j] - mu) * rs * g[tid * 4 + j] + be[tid * 4 + j];
}

extern "C" void kernel_launch(void* const* d_in, const int* in_sizes, int n_in,
                              void* d_out, int out_size, void* d_ws,
                              size_t ws_size, hipStream_t stream) {
  const size_t MB = 1ull << 20;
  if (ws_size < 61 * MB) return;  // proven >= 61 MiB

  const float* text1 = (const float*)d_in[0];
  const float* vis1 = (const float*)d_in[1];
  const float* sc1 = (const float*)d_in[2];
  const float* text2 = (const float*)d_in[3];
  const float* vis2 = (const float*)d_in[4];
  const float* sc2 = (const float*)d_in[5];
  const float* Wq = (const float*)d_in[6];
  const float* bq = (const float*)d_in[7];
  const float* Wk = (const float*)d_in[8];
  const float* bk = (const float*)d_in[9];
  const float* Wv = (const float*)d_in[10];
  const float* bv = (const float*)d_in[11];
  const float* Wo = (const float*)d_in[12];
  const float* bo = (const float*)d_in[13];
  const float* W1 = (const float*)d_in[14];
  const float* b1 = (const float*)d_in[15];
  const float* W2 = (const float*)d_in[16];
  const float* b2 = (const float*)d_in[17];
  const float* g1 = (const float*)d_in[18];
  const float* be1 = (const float*)d_in[19];
  const float* g2 = (const float*)d_in[20];
  const float* be2 = (const float*)d_in[21];

  const int D = 1024, Sv = 196, SvP = 224, DFF = 4096;
  const int M2 = 16384;
  char* w = (char*)d_ws;
  // Algebra (r4): S = text·(K·Wq)^T + (K·bq)^T ; O = P·(V·Wo^T+1·bo^T)^T.
  // FFN = r7 structure (best measured 534.9us): row-chunked H [4096,4096]
  // bf16 with W1b bf16 (r9: raw-f32 W1 regressed +20us/dispatch); F
  // 64x64/BK64 with W2b bf16.
  // ws layout (peak 56 MiB <= proven 61):
  //  [0,16)  pooled bf16 [8192,1024] (persists)
  //  [16,18) Wkb [18,20) Wvb (contiguous: stacked B for KVcat GEMM)
  //  [20,22) Wob [22,24) WqT
  //  [24,..) KVcat [392,2048] 1.53M  [26,..) K2cat [392,1024] 784K
  //  [27,..) VWoT [2048,224] 896K    [28,..) kb f32[448]
  //  [29,36) Spcat bf16 [16384,224] 7 MB
  //  Ocat: d_out (32 MB bf16 scratch; dead until ln_out rewrites it)
  //  Phase B: [16,48) H bf16 [4096,4096]  [48,56) F bf16 [4096,1024]
  //           W1b/W2b in d_out upper [16,32) MB (dead after ln_pool until
  //           ln_out(c=1), which runs after F(c=1), last weight consumer).
  u16* pooled = (u16*)(w + 0 * MB);
  u16* Wkb = (u16*)(w + 16 * MB);  // KVcat B-panel = Wkb..Wvb stacked
  u16* Wvb = (u16*)(w + 18 * MB);
  u16* Wob = (u16*)(w + 20 * MB);
  u16* WqT = (u16*)(w + 22 * MB);
  u16* KVcat = (u16*)(w + 24 * MB);
  u16* K2cat = (u16*)(w + 26 * MB);
  u16* VWoT = (u16*)(w + 27 * MB);
  float* kb = (float*)(w + 28 * MB);
  u16* Spcat = (u16*)(w + 29 * MB);
  u16* Ocat = (u16*)d_out;
  u16* H = (u16*)(w + 16 * MB);
  u16* F = (u16*)(w + 48 * MB);
  u16* W1b = (u16*)((char*)d_out + 16 * MB);
  u16* W2b = (u16*)((char*)d_out + 24 * MB);

  auto grid = [](int m, int n, int tm, int tn) {
    return dim3((unsigned)((n + tn - 1) / tn), (unsigned)((m + tm - 1) / tm));
  };

  // Attention weights to bf16: Wk/Wv/Wo fused (512 blocks each); Wq
  // transposed (needed as K·Wq).
  cvt3_k<<<dim3(3 * 512), 256, 0, stream>>>(Wk, Wkb, Wv, Wvb, Wo, Wob, 512);
  wqt_k<<<dim3(16, 16), 256, 0, stream>>>(Wq, WqT);

  // KVcat[392,2048] = [vis1;vis2](raw f32) @ [Wk;Wv]^T + [bk|bv]
  gemm_db<u16, BIAS_COL2, false, true, false, 64, 64, 32, 256, 8>
      <<<grid(2 * Sv, 2 * D, 64, 64), 256, 0, stream>>>(
          vis1, vis2, Wkb, Wkb, bk, bv, KVcat, 2 * Sv, 2 * D, D, D, D, 2 * Sv,
          2 * D, 2 * D, Sv, 0, D);
  // K2cat[392,1024] = Kcat(lda=2048) @ Wq
  gemm_db<u16, BIAS_NONE, false, false, false, 64, 64, 32, 256, 8>
      <<<grid(2 * Sv, D, 64, 64), 256, 0, stream>>>(
          KVcat, KVcat, WqT, WqT, nullptr, nullptr, K2cat, 2 * Sv, D, D, 2 * D,
          D, 2 * Sv, D, D, 2 * Sv, 0, 0);
  // kb[2][224] = Kcat · bq
  kb_k<<<dim3(112), 256, 0, stream>>>(KVcat, bq, kb, 2 * D);
  // Spcat[16384,ldc=224] = textcat(raw f32) @ K2_br^T + kb_br (row-half)
  gemm_db<u16, BIAS_COL, false, true, false, 64, 64, 32, 256, 8>
      <<<grid(M2, Sv, 64, 64), 256, 0, stream>>>(
          text1, text2, K2cat, K2cat + (size_t)Sv * D, kb, kb + SvP, Spcat, M2,
          Sv, D, D, D, M2, Sv, SvP, 8192, 0, 0);
  // softmax((Sp + score)/8), pad zeros
  softmax_k<<<dim3(M2 / 4), 256, 0, stream>>>(Spcat, sc1, sc2);
  // VWoT[2048,224]: row b*1024+n = Wo[n]·V_br[s] + bo[n]
  gemm_db<u16, BIAS_ROW, false, false, false, 64, 64, 32, 256, 8>
      <<<grid(2 * D, SvP, 64, 64), 256, 0, stream>>>(
          Wob, Wob, KVcat + D, KVcat + (size_t)Sv * 2 * D + D, bo, bo, VWoT,
          2 * D, SvP, D, D, 2 * D, 2 * D, Sv, SvP, D, D - 1, 0);
  // Ocat[16384,1024] = Spcat @ VWoT_br^T, K=224 (d_out scratch) -- 4096 blk
  gemm_db<u16, BIAS_NONE, false, false, false, 64, 64, 32, 256, 8>
      <<<grid(M2, D, 64, 64), 256, 0, stream>>>(
          Spcat, Spcat + (size_t)8192 * SvP, VWoT, VWoT + (size_t)D * SvP,
          nullptr, nullptr, Ocat, M2, D, SvP, SvP, SvP, M2, D, D, 8192, 0, 0);
  // fused both-branch residual + LN + maxpool -> pooled
  ln_pool_k<<<dim3(M2), 256, 0, stream>>>(text1, text2, Ocat, g1, be1, pooled);

  // FFN weights to bf16 (one launch; d_out upper half is dead scratch now).
  cvt3_k<<<dim3(2 * 2048), 256, 0, stream>>>(W1, W1b, W2, W2b, W2, W2b, 2048);

  // FFN in 2 row-chunks of 4096 (r7 structure).
  for (int c = 0; c < 2; ++c) {
    const int r0 = c * 4096, rows = 4096;
    // H = relu(pooled_c @ W1b^T + b1) -- m97 shape: NT=256 128x128
    // (16 MFMA : 8 ds_read per wave-step); LB=5 (LDS cap: 32KB -> 5
    // blocks/CU; VGPR cap 512/5=102 >= 64, no spill). Rider experiment
    // vs r7's LB=4.
    gemm_db<u16, BIAS_COL, true, false, false, 128, 128, 32, 256, 5>
        <<<grid(rows, DFF, 128, 128), 256, 0, stream>>>(
            pooled + (size_t)r0 * D, pooled + (size_t)r0 * D, W1b, W1b, b1, b1,
            H, rows, DFF, D, D, D, rows, DFF, DFF, rows, 0, 0);
    // F = H @ W2b^T + b2 -- 64x64 BK=64 (32KB LDS), lb=5 (LDS cap)
    gemm_db<u16, BIAS_COL, false, false, false, 64, 64, 64, 256, 5>
        <<<grid(rows, D, 64, 64), 256, 0, stream>>>(
            H, H, W2b, W2b, b2, b2, F, rows, D, DFF, DFF, DFF, rows, D, D,
            rows, 0, 0);
    // out_c = LN(pooled_c + F)  f32
    ln_out_k<<<dim3(rows), 256, 0, stream>>>(
        pooled + (size_t)r0 * D, F, g2, be2, (float*)d_out + (size_t)r0 * D);
  }
}

// Round 11
// 521.723 us; speedup vs baseline: 1.2197x; 1.0328x over previous
//
#include <hip/hip_runtime.h>
#include <hip/hip_bf16.h>
#include <cstdint>
#include <type_traits>

typedef unsigned short u16;
typedef __bf16 bf16x8 __attribute__((ext_vector_type(8)));
typedef float f32x4 __attribute__((ext_vector_type(4)));

#define LN_EPS 1e-6f

enum { BIAS_NONE = 0, BIAS_COL = 1, BIAS_ROW = 2, BIAS_COL2 = 3 };

__device__ __forceinline__ float b2f(u16 h) {
  union { unsigned u; float f; } v;
  v.u = ((unsigned)h) << 16;
  return v.f;
}
__device__ __forceinline__ u16 f2b(float x) {
  return __bfloat16_as_ushort(__float2bfloat16(x));
}

__device__ __forceinline__ void gld_lds16(const void* g, void* l) {
  __builtin_amdgcn_global_load_lds(
      (const __attribute__((address_space(1))) void*)g,
      (__attribute__((address_space(3))) void*)l, 16, 0, 0);
}

// 8x f32 -> 8x bf16, one 16B store.
__device__ __forceinline__ void st8(float4 a, float4 b, u16* dst) {
  u16 t[8] = {f2b(a.x), f2b(a.y), f2b(a.z), f2b(a.w),
              f2b(b.x), f2b(b.y), f2b(b.z), f2b(b.w)};
  *reinterpret_cast<uint4*>(dst) = *reinterpret_cast<const uint4*>(t);
}

__device__ __forceinline__ void stage8_cvt(const float* src, size_t off,
                                           u16* dst) {
  const float* p = src + off;
  st8(*reinterpret_cast<const float4*>(p),
      *reinterpret_cast<const float4*>(p + 4), dst);
}

// ==================== 8-phase deep-pipelined GEMM (H) ====================
// C[4096,4096] = relu(A[4096,1024](bf16) · B[4096,1024](bf16)^T + bias).
// 256x256 tile, BK=64 (two 32-col K-halves), 8 waves (2M x 4N), grid
// (16,16)=256 blocks = 1/CU, LDS 128KB. T3+T4 schedule (counted vmcnt,
// raw s_barrier -- NO vmcnt(0) drain in main loop) + T5 setprio.
// Half-tile = [256 rows][32 cols] bf16 = 16KB = 512thr x 2 gld_lds16.
// Stage stream (1 half-tile/phase): tile tau order A.kh0,B.kh0,A.kh1,
// B.kh1; tau's A.kh0 issues 6 phases before first read, B.kh0 5 ahead;
// vmcnt(8) each phase retires everything except the 4 newest phases'
// loads => >=5-phase-old loads landed. Buffer sub-tiles overwritten >=1
// barrier after their last ds_read (reader's lgkmcnt(0) precedes its
// barrier entry). Peeled last iteration drains 8->4->0.
// Swizzle: identical verified 32-col-row chunk XOR ((row>>1)&3), applied
// to global SOURCE col (linear gld_lds dest) and ds_read addr.
// Accumulation order = K ascending by 32 (bit-identical to 2-phase path).
#define PH8(BUF, KS, FH, VM, ...)                                           \
  do {                                                                      \
    asm volatile("s_waitcnt vmcnt(" #VM ")" ::: "memory");                  \
    __builtin_amdgcn_sched_barrier(0);                                      \
    __builtin_amdgcn_s_barrier();                                           \
    __builtin_amdgcn_sched_barrier(0);                                      \
    bf16x8 af[4], bfr[4];                                                   \
    _Pragma("unroll") for (int j = 0; j < 4; j++) {                         \
      const int ra = wm * 128 + ((FH) * 4 + j) * 16 + mrow;                 \
      af[j] = *reinterpret_cast<const bf16x8*>(                             \
          &As[BUF][KS][ra * 32 + ((quad ^ ((ra >> 1) & 3)) << 3)]);         \
    }                                                                       \
    _Pragma("unroll") for (int j = 0; j < 4; j++) {                         \
      const int rb = wn * 64 + j * 16 + mrow;                               \
      bfr[j] = *reinterpret_cast<const bf16x8*>(                            \
          &Bs[BUF][KS][rb * 32 + ((quad ^ ((rb >> 1) & 3)) << 3)]);         \
    }                                                                       \
    __VA_ARGS__;                                                            \
    __builtin_amdgcn_s_setprio(1);                                          \
    _Pragma("unroll") for (int j = 0; j < 4; j++)                           \
        _Pragma("unroll") for (int c = 0; c < 4; c++) acc[(FH) * 4 + j][c] = \
            __builtin_amdgcn_mfma_f32_16x16x32_bf16(                        \
                af[j], bfr[c], acc[(FH) * 4 + j][c], 0, 0, 0);              \
    __builtin_amdgcn_s_setprio(0);                                          \
  } while (0)

__global__ __launch_bounds__(512, 2) void gemm_8p(
    const u16* __restrict__ A, const u16* __restrict__ B,
    const float* __restrict__ bias, u16* __restrict__ C) {
  __shared__ __align__(16) u16 As[2][2][256 * 32];
  __shared__ __align__(16) u16 Bs[2][2][256 * 32];
  const int tid = threadIdx.x;
  const int lane = tid & 63;
  const int wid = tid >> 6;
  const int wm = wid >> 2;
  const int wn = wid & 3;
  const int mrow = lane & 15;
  const int quad = lane >> 4;
  int bxi = blockIdx.x, byi = blockIdx.y;
  {  // bijective XCD swizzle for the fixed 256-block grid
    int wg = byi * 16 + bxi;
    wg = (wg & 7) * 32 + (wg >> 3);
    bxi = wg & 15;
    byi = wg >> 4;
  }
  const int bm = byi * 256;
  const int bn = bxi * 256;

  // staging: thread covers half-tile elems idx0=tid, idx1=512+tid; each
  // idx -> row=idx>>2, 16B chunk=idx&3; source col pre-swizzled.
  const int i0 = tid;
  const int i1 = 512 + tid;
  const int r0 = i0 >> 2, c0s = (((i0 & 3) ^ ((r0 >> 1) & 3)) << 3);
  const int r1 = i1 >> 2, c1s = (((i1 & 3) ^ ((r1 >> 1) & 3)) << 3);
  const size_t oa0 = (size_t)(bm + r0) * 1024 + c0s;
  const size_t oa1 = (size_t)(bm + r1) * 1024 + c1s;
  const size_t ob0 = (size_t)(bn + r0) * 1024 + c0s;
  const size_t ob1 = (size_t)(bn + r1) * 1024 + c1s;

#define STG_A(T, KH)                                                       \
  do {                                                                     \
    gld_lds16(A + oa0 + (T) * 64 + (KH) * 32, &As[(T) & 1][KH][i0 * 8]);   \
    gld_lds16(A + oa1 + (T) * 64 + (KH) * 32, &As[(T) & 1][KH][i1 * 8]);   \
  } while (0)
#define STG_B(T, KH)                                                       \
  do {                                                                     \
    gld_lds16(B + ob0 + (T) * 64 + (KH) * 32, &Bs[(T) & 1][KH][i0 * 8]);   \
    gld_lds16(B + ob1 + (T) * 64 + (KH) * 32, &Bs[(T) & 1][KH][i1 * 8]);   \
  } while (0)

  f32x4 acc[8][4];
#pragma unroll
  for (int i = 0; i < 8; i++)
#pragma unroll
    for (int j = 0; j < 4; j++) acc[i][j] = f32x4{0.f, 0.f, 0.f, 0.f};

  // prologue: tile0 complete + tile1.kh0 (6 half-tiles, 12 loads/thread)
  STG_A(0, 0); STG_B(0, 0); STG_A(0, 1); STG_B(0, 1);
  STG_A(1, 0); STG_B(1, 0);

#pragma unroll 1
  for (int t = 0; t < 14; t += 2) {
    PH8(0, 0, 0, 8, STG_A(t + 1, 1));
    PH8(0, 0, 1, 8, STG_B(t + 1, 1));
    PH8(0, 1, 0, 8, STG_A(t + 2, 0));
    PH8(0, 1, 1, 8, STG_B(t + 2, 0));
    PH8(1, 0, 0, 8, STG_A(t + 2, 1));
    PH8(1, 0, 1, 8, STG_B(t + 2, 1));
    PH8(1, 1, 0, 8, STG_A(t + 3, 0));
    PH8(1, 1, 1, 8, STG_B(t + 3, 0));
  }
  // peeled final iteration (tiles 14,15): staging tapers, drain 8->4->0.
  PH8(0, 0, 0, 8, STG_A(15, 1));
  PH8(0, 0, 1, 8, STG_B(15, 1));
  PH8(0, 1, 0, 8, (void)0);
  PH8(0, 1, 1, 8, (void)0);
  PH8(1, 0, 0, 4, (void)0);
  PH8(1, 0, 1, 4, (void)0);
  PH8(1, 1, 0, 0, (void)0);
  PH8(1, 1, 1, 0, (void)0);

  // epilogue: bias + relu + store (verified C/D mapping)
#pragma unroll
  for (int fr = 0; fr < 8; fr++) {
#pragma unroll
    for (int fc = 0; fc < 4; fc++) {
#pragma unroll
      for (int r = 0; r < 4; r++) {
        const int gr = bm + wm * 128 + fr * 16 + quad * 4 + r;
        const int gc = bn + wn * 64 + fc * 16 + mrow;
        float v = acc[fr][fc][r] + bias[gc];
        v = fmaxf(v, 0.f);
        C[(size_t)gr * 4096 + gc] = f2b(v);
      }
    }
  }
#undef STG_A
#undef STG_B
}

// ==================== 2-phase double-buffered GEMM ====================
// C[M,N](ldc) = A[M,K](lda) * B[N,K](ldb)^T (+bias)(+relu). K mult of BK.
// Dual-operand batching: staged A row r uses (r < Msplit ? A : A2) at local
// row (r - Msplit); B and row-selected bias per block row: bm<Msplit?B:B2.
// BIAS_COL: bp[gc]. BIAS_COL2: gc<colsplit ? bias[gc] : bias2[gc-colsplit].
// BIAS_ROW: bp[gr & rowmask].
// A_RAW/B_RAW: f32 source, global->reg prefetch at loop top, cvt+ds_write
// after MFMA; bf16 source staged via global_load_lds (issued at loop top).
// RAW is ONLY for streamed-once A-panels (r9 lesson).
// LDS 16B-chunk XOR-swizzled with (row>>1)&3 -> 0 bank conflicts (r1).
// LB = occupancy cap (r5), bounded by L2 working set (r8).
template <typename OutT, int BIAS, bool RELU, bool A_RAW, bool B_RAW, int TM,
          int TN, int BK, int NT, int LB>
__global__ __launch_bounds__(NT, LB) void gemm_db(
    const void* __restrict__ A, const void* __restrict__ A2,
    const void* __restrict__ B, const void* __restrict__ B2,
    const float* __restrict__ bias, const float* __restrict__ bias2,
    OutT* __restrict__ C, int M, int N, int K, int lda, int ldb, int MA,
    int NB, int ldc, int Msplit, int rowmask, int colsplit) {
  constexpr int SA = (TM * BK) / (NT * 8);  // A staging slots
  constexpr int SB = (TN * BK) / (NT * 8);
  constexpr int AI = (NT == 512) ? 2 : ((TM == 128 && TN == 128) ? 4 : 2);
  constexpr int BJ = (TM == 64 && TN == 64) ? 2 : 4;
  __shared__ __align__(16) u16 As[2][TM * BK];
  __shared__ __align__(16) u16 Bs[2][TN * BK];
  const int tid = threadIdx.x;
  const int lane = tid & 63;
  const int wv = tid >> 6;
  int wr, wc;
  if constexpr (NT == 512) {
    wr = (wv & 3) * 32; wc = (wv >> 2) * 64;
  } else if constexpr (TM == 128 && TN == 128) {
    wr = (wv >> 1) * 64; wc = (wv & 1) * 64;
  } else if constexpr (TM == 128 && TN == 64) {
    wr = wv * 32; wc = 0;
  } else {
    wr = (wv >> 1) * 32; wc = (wv & 1) * 32;
  }
  const int mrow = lane & 15;
  const int quad = lane >> 4;

  // Bijective XCD swizzle (all grids here are %8==0; identity otherwise).
  int bxi = blockIdx.x, byi = blockIdx.y;
  {
    const int gx = (int)gridDim.x;
    const int nwg = gx * (int)gridDim.y;
    if ((nwg & 7) == 0) {
      int wg = byi * gx + bxi;
      wg = (wg & 7) * (nwg >> 3) + (wg >> 3);
      bxi = wg % gx;
      byi = wg / gx;
    }
  }
  const int bm = byi * TM;
  const int bn = bxi * TN;

  f32x4 acc[AI][BJ];
#pragma unroll
  for (int i = 0; i < AI; i++)
#pragma unroll
    for (int j = 0; j < BJ; j++) acc[i][j] = f32x4{0.f, 0.f, 0.f, 0.f};

  const int e0 = tid * 8;
  const int r0t = e0 >> 5;
  const int swc8 = ((((e0 >> 3) & 3) ^ ((r0t >> 1) & 3)) << 3);

  const void* Asrc[SA];
  size_t aoff[SA];
#pragma unroll
  for (int s = 0; s < SA; s++) {
    const int h = (s * NT * 8) / (TM * 32);
    const int rb = ((s * NT * 8) % (TM * 32)) >> 5;
    int ra = bm + rb + r0t;
    if (ra >= MA) ra = MA - 1;
    Asrc[s] = (ra < Msplit) ? A : A2;
    const int rr = (ra < Msplit) ? ra : ra - Msplit;
    aoff[s] = (size_t)rr * lda + h * 32 + swc8;
  }
  const void* Bb = (bm < Msplit) ? B : B2;
  size_t boff[SB];
#pragma unroll
  for (int s = 0; s < SB; s++) {
    const int h = (s * NT * 8) / (TN * 32);
    const int rb = ((s * NT * 8) % (TN * 32)) >> 5;
    int rbn = bn + rb + r0t;
    if (rbn >= NB) rbn = NB - 1;
    boff[s] = (size_t)rbn * ldb + h * 32 + swc8;
  }

  // ---- prologue: stage k=0 into buffer 0
#pragma unroll
  for (int s = 0; s < SA; s++) {
    if constexpr (A_RAW) {
      const float* p = (const float*)Asrc[s] + aoff[s];
      st8(*reinterpret_cast<const float4*>(p),
          *reinterpret_cast<const float4*>(p + 4), &As[0][s * NT * 8 + e0]);
    } else {
      gld_lds16((const u16*)Asrc[s] + aoff[s], &As[0][s * NT * 8 + e0]);
    }
  }
#pragma unroll
  for (int s = 0; s < SB; s++) {
    if constexpr (B_RAW) {
      const float* p = (const float*)Bb + boff[s];
      st8(*reinterpret_cast<const float4*>(p),
          *reinterpret_cast<const float4*>(p + 4), &Bs[0][s * NT * 8 + e0]);
    } else {
      gld_lds16((const u16*)Bb + boff[s], &Bs[0][s * NT * 8 + e0]);
    }
  }
  __syncthreads();

  const int so = ((quad ^ ((mrow >> 1) & 3)) << 3);

  int cur = 0;
  for (int k0 = 0; k0 < K; k0 += BK) {
    const int nk = k0 + BK;
    const bool pf = nk < K;
    float4 fA[SA][2], fB[SB][2];
    if (pf) {
#pragma unroll
      for (int s = 0; s < SA; s++) {
        if constexpr (A_RAW) {
          const float* p = (const float*)Asrc[s] + aoff[s] + nk;
          fA[s][0] = *reinterpret_cast<const float4*>(p);
          fA[s][1] = *reinterpret_cast<const float4*>(p + 4);
        } else {
          gld_lds16((const u16*)Asrc[s] + aoff[s] + nk,
                    &As[cur ^ 1][s * NT * 8 + e0]);
        }
      }
#pragma unroll
      for (int s = 0; s < SB; s++) {
        if constexpr (B_RAW) {
          const float* p = (const float*)Bb + boff[s] + nk;
          fB[s][0] = *reinterpret_cast<const float4*>(p);
          fB[s][1] = *reinterpret_cast<const float4*>(p + 4);
        } else {
          gld_lds16((const u16*)Bb + boff[s] + nk,
                    &Bs[cur ^ 1][s * NT * 8 + e0]);
        }
      }
    }
#pragma unroll
    for (int h = 0; h < BK / 32; h++) {
      bf16x8 af[AI], bfm[BJ];
#pragma unroll
      for (int i = 0; i < AI; i++)
        af[i] = *reinterpret_cast<const bf16x8*>(
            &As[cur][h * TM * 32 + (wr + i * 16 + mrow) * 32 + so]);
#pragma unroll
      for (int j = 0; j < BJ; j++)
        bfm[j] = *reinterpret_cast<const bf16x8*>(
            &Bs[cur][h * TN * 32 + (wc + j * 16 + mrow) * 32 + so]);
#pragma unroll
      for (int i = 0; i < AI; i++)
#pragma unroll
        for (int j = 0; j < BJ; j++)
          acc[i][j] = __builtin_amdgcn_mfma_f32_16x16x32_bf16(
              af[i], bfm[j], acc[i][j], 0, 0, 0);
    }
    if (pf) {
      if constexpr (A_RAW) {
#pragma unroll
        for (int s = 0; s < SA; s++)
          st8(fA[s][0], fA[s][1], &As[cur ^ 1][s * NT * 8 + e0]);
      }
      if constexpr (B_RAW) {
#pragma unroll
        for (int s = 0; s < SB; s++)
          st8(fB[s][0], fB[s][1], &Bs[cur ^ 1][s * NT * 8 + e0]);
      }
    }
    __syncthreads();
    cur ^= 1;
  }

  const float* bp = (bm < Msplit) ? bias : bias2;
#pragma unroll
  for (int i = 0; i < AI; i++) {
#pragma unroll
    for (int j = 0; j < BJ; j++) {
#pragma unroll
      for (int r = 0; r < 4; r++) {
        const int gr = bm + wr + i * 16 + quad * 4 + r;
        const int gc = bn + wc + j * 16 + mrow;
        if (gr < M && gc < N) {
          float v = acc[i][j][r];
          if (BIAS == BIAS_COL) v += bp[gc];
          if (BIAS == BIAS_COL2)
            v += (gc < colsplit) ? bias[gc] : bias2[gc - colsplit];
          if (BIAS == BIAS_ROW) v += bp[gr & rowmask];
          if (RELU) v = fmaxf(v, 0.f);
          if constexpr (std::is_same<OutT, float>::value)
            C[(size_t)gr * ldc + gc] = v;
          else
            C[(size_t)gr * ldc + gc] = f2b(v);
        }
      }
    }
  }
}

// Up-to-3-segment f32 -> bf16 bulk conversion; blocksPer blocks/segment.
__global__ __launch_bounds__(256) void cvt3_k(
    const float* __restrict__ s0, u16* __restrict__ d0,
    const float* __restrict__ s1, u16* __restrict__ d1,
    const float* __restrict__ s2, u16* __restrict__ d2, int blocksPer) {
  const int seg = blockIdx.x / blocksPer;
  const int b = blockIdx.x % blocksPer;
  const float* s = (seg == 0) ? s0 : ((seg == 1) ? s1 : s2);
  u16* d = (seg == 0) ? d0 : ((seg == 1) ? d1 : d2);
  const size_t i = ((size_t)b * 256 + threadIdx.x) * 8;
  stage8_cvt(s, i, d + i);
}

// Transposed bf16 conversion: dst[d][j] = bf16(src[j][d]), 1024x1024.
__global__ __launch_bounds__(256) void wqt_k(const float* __restrict__ src,
                                             u16* __restrict__ dst) {
  __shared__ float t[64][65];
  const int bx = blockIdx.x;
  const int by = blockIdx.y;
  const int tx = threadIdx.x & 63;
  const int ty = threadIdx.x >> 6;
#pragma unroll
  for (int i = 0; i < 16; i++)
    t[ty * 16 + i][tx] =
        src[(size_t)(by * 64 + ty * 16 + i) * 1024 + bx * 64 + tx];
  __syncthreads();
#pragma unroll
  for (int i = 0; i < 16; i++)
    dst[(size_t)(bx * 64 + ty * 16 + i) * 1024 + by * 64 + tx] =
        f2b(t[tx][ty * 16 + i]);
}

// kb[b*224+s] = sum_j bf16(Kc[(b*196+s)*ld + j]) * bq[j] (s<196; else 0).
__global__ __launch_bounds__(256) void kb_k(const u16* __restrict__ Kc,
                                            const float* __restrict__ bq,
                                            float* __restrict__ kb, int ld) {
  const int wvi = blockIdx.x * 4 + (threadIdx.x >> 6);
  const int lane = threadIdx.x & 63;
  const int b = wvi / 224, s = wvi % 224;
  float sum = 0.f;
  if (s < 196) {
    const u16* row = Kc + (size_t)(b * 196 + s) * ld;
    for (int j = lane; j < 1024; j += 64) sum += b2f(row[j]) * bq[j];
  }
#pragma unroll
  for (int off = 32; off > 0; off >>= 1) sum += __shfl_xor(sum, off);
  if (lane == 0) kb[wvi] = sum;
}

// In-place softmax over Sp[row, 0..224) bf16 (16384 batched rows).
__global__ __launch_bounds__(256) void softmax_k(
    u16* __restrict__ Sp, const float* __restrict__ sc1,
    const float* __restrict__ sc2) {
  const int row = blockIdx.x * 4 + (threadIdx.x >> 6);
  const int lane = threadIdx.x & 63;
  const float* score = (row < 8192) ? sc1 + (size_t)row * 196
                                    : sc2 + (size_t)(row - 8192) * 196;
  float x[4];
  float mx = -1e30f;
#pragma unroll
  for (int t = 0; t < 4; t++) {
    const int s = lane + 64 * t;
    float v = -1e30f;
    if (s < 196) v = (b2f(Sp[(size_t)row * 224 + s]) + score[s]) * 0.125f;
    x[t] = v;
    mx = fmaxf(mx, v);
  }
#pragma unroll
  for (int off = 32; off > 0; off >>= 1) mx = fmaxf(mx, __shfl_xor(mx, off));
  float sum = 0.f;
#pragma unroll
  for (int t = 0; t < 4; t++) {
    const int s = lane + 64 * t;
    const float e = (s < 196) ? expf(x[t] - mx) : 0.f;
    x[t] = e;
    sum += e;
  }
#pragma unroll
  for (int off = 32; off > 0; off >>= 1) sum += __shfl_xor(sum, off);
  const float inv = 1.f / sum;
#pragma unroll
  for (int t = 0; t < 4; t++) {
    const int s = lane + 64 * t;
    if (s < 224) Sp[(size_t)row * 224 + s] = f2b((s < 196) ? x[t] * inv : 0.f);
  }
}

// Fused both-branch residual-LN-pool.
__global__ __launch_bounds__(256) void ln_pool_k(
    const float* __restrict__ X1, const float* __restrict__ X2,
    const u16* __restrict__ Y, const float* __restrict__ g,
    const float* __restrict__ be, u16* __restrict__ pooled) {
  const int row16 = blockIdx.x;
  const int br = row16 >> 13;
  const int row = row16 & 8191;
  const int tid = threadIdx.x;
  const int lane = tid & 63;
  const int wv = tid >> 6;
  const float* X = (br ? X2 : X1) + (size_t)row * 1024;
  const u16* Yp = Y + (size_t)row16 * 1024;
  __shared__ float red[4];
  float v[4];
  float s = 0.f;
#pragma unroll
  for (int j = 0; j < 4; j++) {
    const float a = X[tid * 4 + j] + b2f(Yp[tid * 4 + j]);
    v[j] = a;
    s += a;
  }
#pragma unroll
  for (int off = 32; off > 0; off >>= 1) s += __shfl_xor(s, off);
  if (lane == 0) red[wv] = s;
  __syncthreads();
  const float mu = (red[0] + red[1] + red[2] + red[3]) * (1.f / 1024.f);
  __syncthreads();
  float var = 0.f;
#pragma unroll
  for (int j = 0; j < 4; j++) {
    const float d = v[j] - mu;
    var += d * d;
  }
#pragma unroll
  for (int off = 32; off > 0; off >>= 1) var += __shfl_xor(var, off);
  if (lane == 0) red[wv] = var;
  __syncthreads();
  var = (red[0] + red[1] + red[2] + red[3]) * (1.f / 1024.f);
  const float rs = rsqrtf(var + LN_EPS);
  float n[4];
#pragma unroll
  for (int j = 0; j < 4; j++)
    n[j] = (v[j] - mu) * rs * g[tid * 4 + j] + be[tid * 4 + j];
  const size_t pb = (size_t)row * 1024 + br * 512 + tid * 2;
  pooled[pb] = f2b(fmaxf(n[0], n[1]));
  pooled[pb + 1] = f2b(fmaxf(n[2], n[3]));
}

// out(f32) = LN(X(bf16) + Y(bf16))*g + be over D=1024.
__global__ __launch_bounds__(256) void ln_out_k(
    const u16* __restrict__ X, const u16* __restrict__ Y,
    const float* __restrict__ g, const float* __restrict__ be,
    float* __restrict__ out) {
  const int row = blockIdx.x;
  const int tid = threadIdx.x;
  const int lane = tid & 63;
  const int wv = tid >> 6;
  __shared__ float red[4];
  float v[4];
  float s = 0.f;
  const size_t base = (size_t)row * 1024 + tid * 4;
#pragma unroll
  for (int j = 0; j < 4; j++) {
    const float a = b2f(X[base + j]) + b2f(Y[base + j]);
    v[j] = a;
    s += a;
  }
#pragma unroll
  for (int off = 32; off > 0; off >>= 1) s += __shfl_xor(s, off);
  if (lane == 0) red[wv] = s;
  __syncthreads();
  const float mu = (red[0] + red[1] + red[2] + red[3]) * (1.f / 1024.f);
  __syncthreads();
  float var = 0.f;
#pragma unroll
  for (int j = 0; j < 4; j++) {
    const float d = v[j] - mu;
    var += d * d;
  }
#pragma unroll
  for (int off = 32; off > 0; off >>= 1) var += __shfl_xor(var, off);
  if (lane == 0) red[wv] = var;
  __syncthreads();
  var = (red[0] + red[1] + red[2] + red[3]) * (1.f / 1024.f);
  const float rs = rsqrtf(var + LN_EPS);
#pragma unroll
  for (int j = 0; j < 4; j++)
    out[base + j] = (v[j] - mu) * rs * g[tid * 4 + j] + be[tid * 4 + j];
}

extern "C" void kernel_launch(void* const* d_in, const int* in_sizes, int n_in,
                              void* d_out, int out_size, void* d_ws,
                              size_t ws_size, hipStream_t stream) {
  const size_t MB = 1ull << 20;
  if (ws_size < 61 * MB) return;  // proven >= 61 MiB

  const float* text1 = (const float*)d_in[0];
  const float* vis1 = (const float*)d_in[1];
  const float* sc1 = (const float*)d_in[2];
  const float* text2 = (const float*)d_in[3];
  const float* vis2 = (const float*)d_in[4];
  const float* sc2 = (const float*)d_in[5];
  const float* Wq = (const float*)d_in[6];
  const float* bq = (const float*)d_in[7];
  const float* Wk = (const float*)d_in[8];
  const float* bk = (const float*)d_in[9];
  const float* Wv = (const float*)d_in[10];
  const float* bv = (const float*)d_in[11];
  const float* Wo = (const float*)d_in[12];
  const float* bo = (const float*)d_in[13];
  const float* W1 = (const float*)d_in[14];
  const float* b1 = (const float*)d_in[15];
  const float* W2 = (const float*)d_in[16];
  const float* b2 = (const float*)d_in[17];
  const float* g1 = (const float*)d_in[18];
  const float* be1 = (const float*)d_in[19];
  const float* g2 = (const float*)d_in[20];
  const float* be2 = (const float*)d_in[21];

  const int D = 1024, Sv = 196, SvP = 224, DFF = 4096;
  const int M2 = 16384;
  char* w = (char*)d_ws;
  // Algebra (r4): S = text·(K·Wq)^T + (K·bq)^T ; O = P·(V·Wo^T+1·bo^T)^T.
  // FFN: H via 8-phase 256^2 kernel (r11); F 64x64/BK64 bf16 (r7 best).
  // ws layout (peak 56 MiB <= proven 61):
  //  [0,16)  pooled bf16 [8192,1024] (persists)
  //  [16,18) Wkb [18,20) Wvb (stacked B for KVcat)  [20,22) Wob [22,24) WqT
  //  [24,..) KVcat [392,2048]  [26,..) K2cat [392,1024]
  //  [27,..) VWoT [2048,224]   [28,..) kb f32[448]
  //  [29,36) Spcat bf16 [16384,224]
  //  Ocat: d_out (bf16 scratch; dead until ln_out rewrites it)
  //  Phase B: [16,48) H bf16 [4096,4096]  [48,56) F bf16 [4096,1024]
  //           W1b/W2b in d_out upper [16,32) MB (dead after ln_pool until
  //           ln_out(c=1), which runs after F(c=1), last weight consumer).
  u16* pooled = (u16*)(w + 0 * MB);
  u16* Wkb = (u16*)(w + 16 * MB);
  u16* Wvb = (u16*)(w + 18 * MB);
  u16* Wob = (u16*)(w + 20 * MB);
  u16* WqT = (u16*)(w + 22 * MB);
  u16* KVcat = (u16*)(w + 24 * MB);
  u16* K2cat = (u16*)(w + 26 * MB);
  u16* VWoT = (u16*)(w + 27 * MB);
  float* kb = (float*)(w + 28 * MB);
  u16* Spcat = (u16*)(w + 29 * MB);
  u16* Ocat = (u16*)d_out;
  u16* H = (u16*)(w + 16 * MB);
  u16* F = (u16*)(w + 48 * MB);
  u16* W1b = (u16*)((char*)d_out + 16 * MB);
  u16* W2b = (u16*)((char*)d_out + 24 * MB);

  auto grid = [](int m, int n, int tm, int tn) {
    return dim3((unsigned)((n + tn - 1) / tn), (unsigned)((m + tm - 1) / tm));
  };

  cvt3_k<<<dim3(3 * 512), 256, 0, stream>>>(Wk, Wkb, Wv, Wvb, Wo, Wob, 512);
  wqt_k<<<dim3(16, 16), 256, 0, stream>>>(Wq, WqT);

  // KVcat[392,2048] = [vis1;vis2](raw f32) @ [Wk;Wv]^T + [bk|bv]
  gemm_db<u16, BIAS_COL2, false, true, false, 64, 64, 32, 256, 8>
      <<<grid(2 * Sv, 2 * D, 64, 64), 256, 0, stream>>>(
          vis1, vis2, Wkb, Wkb, bk, bv, KVcat, 2 * Sv, 2 * D, D, D, D, 2 * Sv,
          2 * D, 2 * D, Sv, 0, D);
  // K2cat[392,1024] = Kcat(lda=2048) @ Wq
  gemm_db<u16, BIAS_NONE, false, false, false, 64, 64, 32, 256, 8>
      <<<grid(2 * Sv, D, 64, 64), 256, 0, stream>>>(
          KVcat, KVcat, WqT, WqT, nullptr, nullptr, K2cat, 2 * Sv, D, D, 2 * D,
          D, 2 * Sv, D, D, 2 * Sv, 0, 0);
  // kb[2][224] = Kcat · bq
  kb_k<<<dim3(112), 256, 0, stream>>>(KVcat, bq, kb, 2 * D);
  // Spcat[16384,ldc=224] = textcat(raw f32) @ K2_br^T + kb_br (row-half)
  gemm_db<u16, BIAS_COL, false, true, false, 64, 64, 32, 256, 8>
      <<<grid(M2, Sv, 64, 64), 256, 0, stream>>>(
          text1, text2, K2cat, K2cat + (size_t)Sv * D, kb, kb + SvP, Spcat, M2,
          Sv, D, D, D, M2, Sv, SvP, 8192, 0, 0);
  // softmax((Sp + score)/8), pad zeros
  softmax_k<<<dim3(M2 / 4), 256, 0, stream>>>(Spcat, sc1, sc2);
  // VWoT[2048,224]: row b*1024+n = Wo[n]·V_br[s] + bo[n]
  gemm_db<u16, BIAS_ROW, false, false, false, 64, 64, 32, 256, 8>
      <<<grid(2 * D, SvP, 64, 64), 256, 0, stream>>>(
          Wob, Wob, KVcat + D, KVcat + (size_t)Sv * 2 * D + D, bo, bo, VWoT,
          2 * D, SvP, D, D, 2 * D, 2 * D, Sv, SvP, D, D - 1, 0);
  // Ocat[16384,1024] = Spcat @ VWoT_br^T, K=224 (d_out scratch)
  gemm_db<u16, BIAS_NONE, false, false, false, 64, 64, 32, 256, 8>
      <<<grid(M2, D, 64, 64), 256, 0, stream>>>(
          Spcat, Spcat + (size_t)8192 * SvP, VWoT, VWoT + (size_t)D * SvP,
          nullptr, nullptr, Ocat, M2, D, SvP, SvP, SvP, M2, D, D, 8192, 0, 0);
  // fused both-branch residual + LN + maxpool -> pooled
  ln_pool_k<<<dim3(M2), 256, 0, stream>>>(text1, text2, Ocat, g1, be1, pooled);

  // FFN weights to bf16 (d_out upper half is dead scratch now).
  cvt3_k<<<dim3(2 * 2048), 256, 0, stream>>>(W1, W1b, W2, W2b, W2, W2b, 2048);

  // FFN in 2 row-chunks of 4096.
  for (int c = 0; c < 2; ++c) {
    const int r0 = c * 4096, rows = 4096;
    // H = relu(pooled_c @ W1b^T + b1) -- 8-phase 256^2 kernel, grid (16,16)
    gemm_8p<<<dim3(16, 16), 512, 0, stream>>>(pooled + (size_t)r0 * D, W1b,
                                              b1, H);
    // F = H @ W2b^T + b2 -- 64x64 BK=64 (32KB LDS), lb=5 (LDS cap)
    gemm_db<u16, BIAS_COL, false, false, false, 64, 64, 64, 256, 5>
        <<<grid(rows, D, 64, 64), 256, 0, stream>>>(
            H, H, W2b, W2b, b2, b2, F, rows, D, DFF, DFF, DFF, rows, D, D,
            rows, 0, 0);
    // out_c = LN(pooled_c + F)  f32
    ln_out_k<<<dim3(rows), 256, 0, stream>>>(
        pooled + (size_t)r0 * D, F, g2, be2, (float*)d_out + (size_t)r0 * D);
  }
}